// Round 1
// baseline (2987.936 us; speedup 1.0000x reference)
//
#include <hip/hip_runtime.h>
#include <math.h>

typedef __attribute__((ext_vector_type(8))) short short8;
typedef __attribute__((ext_vector_type(4))) float f32x4;

#define USER_NUM_  100000
#define COMP_NUM_  50000
#define ENTITY_NUM_ 150002
#define REL_NUM_   200
#define DD         128
#define TT         12
#define EE         250000
#define SS         20000
#define BB         1024

__device__ inline short f2bf(float f) {
    unsigned u = __float_as_uint(f);
    unsigned r = (u + 0x7fffu + ((u >> 16) & 1u)) >> 16;
    return (short)r;
}

__device__ inline short8 pack_bf8(float4 a, float4 b) {
    short8 r;
    r[0] = f2bf(a.x); r[1] = f2bf(a.y); r[2] = f2bf(a.z); r[3] = f2bf(a.w);
    r[4] = f2bf(b.x); r[5] = f2bf(b.y); r[6] = f2bf(b.z); r[7] = f2bf(b.w);
    return r;
}

__device__ inline float sigmoidf_(float x) { return 1.f / (1.f + __expf(-x)); }

__device__ inline void lse_push(float v, float& m, float& s) {
    if (v <= m) { s += __expf(v - m); }
    else { s = s * __expf(m - v) + 1.f; m = v; }
}

// ---------------- utility kernels ----------------
__global__ __launch_bounds__(256) void copy4_k(float4* __restrict__ dst, const float4* __restrict__ src, int n4) {
    int i = blockIdx.x * 256 + threadIdx.x;
    if (i < n4) dst[i] = src[i];
}

__global__ __launch_bounds__(256) void zero_i32_k(int* __restrict__ p, int n) {
    int i = blockIdx.x * 256 + threadIdx.x;
    if (i < n) p[i] = 0;
}

__global__ __launch_bounds__(256) void prepW_k(const float* __restrict__ Wih, const float* __restrict__ Whh,
                                               const float* __restrict__ bih, const float* __restrict__ bhh,
                                               short* __restrict__ Wt, float* __restrict__ bsum) {
    int n = blockIdx.x;      // 0..511
    int k = threadIdx.x;     // 0..255
    float v = (k < 128) ? Wih[n * 128 + k] : Whh[n * 128 + (k - 128)];
    Wt[n * 256 + k] = f2bf(v);
    if (k == 0) bsum[n] = bih[n] + bhh[n];
}

__global__ __launch_bounds__(256) void hist_k(int* __restrict__ cnt, const int* __restrict__ dst, int n) {
    int i = blockIdx.x * 256 + threadIdx.x;
    if (i < n) atomicAdd(&cnt[dst[i]], 1);
}

__global__ __launch_bounds__(256) void inv_k(const int* __restrict__ cnt, float* __restrict__ invp, int n) {
    int i = blockIdx.x * 256 + threadIdx.x;
    if (i < n) {
        int c = cnt[i];
        invp[i] = 1.f / (float)(c > 1 ? c : 1);
    }
}

// ---------------- scatter: h_new[d] += h_old[s]*rel[r]*inv[d] ----------------
__global__ __launch_bounds__(256) void scatter_k(const float* __restrict__ hold, float* __restrict__ hnew,
                                                 const float* __restrict__ relemb, const float* __restrict__ invp,
                                                 const int* __restrict__ src, const int* __restrict__ dst,
                                                 const int* __restrict__ rel) {
    int idx = blockIdx.x * 256 + threadIdx.x;
    int e = idx >> 7;
    int k = idx & 127;
    if (e >= EE) return;
    int s = src[e], d = dst[e], r = rel[e];
    float m = hold[s * DD + k] * relemb[r * DD + k] * invp[d];
    atomicAdd(&hnew[(size_t)d * DD + k], m);
}

// ---------------- LSTM on seed rows (MFMA bf16) ----------------
// gates = [xi|hp] @ Wt^T + bsum ; Wt is [512][256] bf16 row-major.
// Block: 32 seeds, 4 waves. Wave w owns units d in [32w, 32w+32): all 4 gates land in-lane.
__global__ __launch_bounds__(256) void lstm_k(const float* __restrict__ hold, float* __restrict__ hnew,
                                              float* __restrict__ cbuf, const short* __restrict__ Wt,
                                              const float* __restrict__ bsum, const int* __restrict__ seed) {
    int w = threadIdx.x >> 6;
    int lane = threadIdx.x & 63;
    int lrow = lane & 15, lhi = lane >> 4;
    int m0 = blockIdx.x * 32;
    int w32 = w * 32;

    const float* pxi[2];
    const float* php[2];
#pragma unroll
    for (int mi = 0; mi < 2; ++mi) {
        int m = m0 + mi * 16 + lrow;
        int sd = seed[m];
        pxi[mi] = hnew + (size_t)sd * DD;
        php[mi] = hold + (size_t)sd * DD;
    }

    f32x4 acc[2][4][2];
#pragma unroll
    for (int mi = 0; mi < 2; ++mi)
#pragma unroll
        for (int g = 0; g < 4; ++g)
#pragma unroll
            for (int s = 0; s < 2; ++s)
                acc[mi][g][s] = (f32x4){0.f, 0.f, 0.f, 0.f};

#pragma unroll
    for (int kk = 0; kk < 8; ++kk) {
        int klane = kk * 32 + lhi * 8;
        short8 af[2];
#pragma unroll
        for (int mi = 0; mi < 2; ++mi) {
            const float* p = (klane < 128) ? (pxi[mi] + klane) : (php[mi] + (klane - 128));
            float4 a = *(const float4*)p;
            float4 b = *(const float4*)(p + 4);
            af[mi] = pack_bf8(a, b);
        }
#pragma unroll
        for (int g = 0; g < 4; ++g)
#pragma unroll
            for (int s = 0; s < 2; ++s) {
                int col = g * 128 + w32 + s * 16 + lrow;
                short8 bf = *(const short8*)(Wt + col * 256 + klane);
                acc[0][g][s] = __builtin_amdgcn_mfma_f32_16x16x32_bf16(af[0], bf, acc[0][g][s], 0, 0, 0);
                acc[1][g][s] = __builtin_amdgcn_mfma_f32_16x16x32_bf16(af[1], bf, acc[1][g][s], 0, 0, 0);
            }
    }

    __syncthreads();  // all xi reads done before seed rows are overwritten

#pragma unroll
    for (int mi = 0; mi < 2; ++mi) {
#pragma unroll
        for (int r = 0; r < 4; ++r) {
            int m = m0 + mi * 16 + lhi * 4 + r;
            int sd = seed[m];
#pragma unroll
            for (int s = 0; s < 2; ++s) {
                int d = w32 + s * 16 + lrow;
                float ig = acc[mi][0][s][r] + bsum[d];
                float fg = acc[mi][1][s][r] + bsum[128 + d];
                float gg = acc[mi][2][s][r] + bsum[256 + d];
                float og = acc[mi][3][s][r] + bsum[384 + d];
                float cp = cbuf[(size_t)sd * DD + d];
                float cn = sigmoidf_(fg) * cp + sigmoidf_(ig) * tanhf(gg);
                float hn = sigmoidf_(og) * tanhf(cn);
                cbuf[(size_t)sd * DD + d] = cn;
                hnew[(size_t)sd * DD + d] = hn;
            }
        }
    }
}

// ---------------- comp loss partials: online LSE over 50000 comps ----------------
// grid: (64 user-groups of 16, 8 comp partitions of 6250). Block 256 threads.
__global__ __launch_bounds__(256) void comp_partial_k(const float* __restrict__ hfin, const float* __restrict__ ent,
                                                      const int* __restrict__ ub, float* __restrict__ partm,
                                                      float* __restrict__ parts) {
    __shared__ float u_lds[16][128];
    __shared__ float lm[16][256];
    __shared__ float ls[16][256];
    int tid = threadIdx.x;
    int ug = blockIdx.x;
    int p = blockIdx.y;

    for (int i = tid; i < 16 * 32; i += 256) {
        int uu = i >> 5, kk = i & 31;
        int row = ub[ug * 16 + uu];
        ((float4*)&u_lds[uu][0])[kk] = ((const float4*)(hfin + (size_t)row * DD))[kk];
    }
    __syncthreads();

    float mr[16], sr[16];
#pragma unroll
    for (int u = 0; u < 16; ++u) { mr[u] = -1e30f; sr[u] = 0.f; }

    int cbase = p * 6250, cend = cbase + 6250;
    for (int it = 0; it < 13; ++it) {
        int c0 = cbase + it * 512 + tid;
        int c1 = c0 + 256;
        bool v0 = c0 < cend, v1 = c1 < cend;
        if (!v0) continue;
        float a0[16], a1[16];
#pragma unroll
        for (int u = 0; u < 16; ++u) { a0[u] = 0.f; a1[u] = 0.f; }
        const float4* cr0 = (const float4*)(ent + (size_t)(USER_NUM_ + c0) * DD);
        const float4* cr1 = (const float4*)(ent + (size_t)(USER_NUM_ + c1) * DD);
        if (v1) {
#pragma unroll 8
            for (int kk = 0; kk < 32; ++kk) {
                float4 cv0 = cr0[kk];
                float4 cv1 = cr1[kk];
#pragma unroll
                for (int u = 0; u < 16; ++u) {
                    float4 uv = *(const float4*)&u_lds[u][kk * 4];
                    a0[u] = fmaf(uv.x, cv0.x, fmaf(uv.y, cv0.y, fmaf(uv.z, cv0.z, fmaf(uv.w, cv0.w, a0[u]))));
                    a1[u] = fmaf(uv.x, cv1.x, fmaf(uv.y, cv1.y, fmaf(uv.z, cv1.z, fmaf(uv.w, cv1.w, a1[u]))));
                }
            }
#pragma unroll
            for (int u = 0; u < 16; ++u) { lse_push(a0[u], mr[u], sr[u]); lse_push(a1[u], mr[u], sr[u]); }
        } else {
#pragma unroll 8
            for (int kk = 0; kk < 32; ++kk) {
                float4 cv0 = cr0[kk];
#pragma unroll
                for (int u = 0; u < 16; ++u) {
                    float4 uv = *(const float4*)&u_lds[u][kk * 4];
                    a0[u] = fmaf(uv.x, cv0.x, fmaf(uv.y, cv0.y, fmaf(uv.z, cv0.z, fmaf(uv.w, cv0.w, a0[u]))));
                }
            }
#pragma unroll
            for (int u = 0; u < 16; ++u) lse_push(a0[u], mr[u], sr[u]);
        }
    }

#pragma unroll
    for (int u = 0; u < 16; ++u) { lm[u][tid] = mr[u]; ls[u][tid] = sr[u]; }
    __syncthreads();

    if (tid < 16) {
        int u = tid;
        float M = -1e30f, SSm = 0.f;
        for (int t = 0; t < 256; ++t) {
            float m2 = lm[u][t], s2 = ls[u][t];
            if (s2 > 0.f) {
                if (m2 <= M) SSm += s2 * __expf(m2 - M);
                else { SSm = SSm * __expf(M - m2) + s2; M = m2; }
            }
        }
        partm[(ug * 16 + u) * 8 + p] = M;
        parts[(ug * 16 + u) * 8 + p] = SSm;
    }
}

// ---------------- finish: merge partials, pos terms, job loss, atomic out ----------------
__global__ __launch_bounds__(256) void finish_k(const float* __restrict__ hfin, const float* __restrict__ ent,
                                                const float* __restrict__ rel, const int* __restrict__ ub,
                                                const int* __restrict__ ct, const int* __restrict__ jt,
                                                const float* __restrict__ partm, const float* __restrict__ parts,
                                                float* __restrict__ out) {
    int u = blockIdx.x * 256 + threadIdx.x;
    if (u >= BB) return;

    const float4* uvp = (const float4*)(hfin + (size_t)ub[u] * DD);
    float4 uv[32];
#pragma unroll
    for (int i = 0; i < 32; ++i) uv[i] = uvp[i];

    // pos_c
    const float4* tc = (const float4*)(ent + (size_t)(USER_NUM_ + ct[u]) * DD);
    float pc = 0.f;
#pragma unroll
    for (int i = 0; i < 32; ++i) {
        float4 c4 = tc[i];
        pc = fmaf(uv[i].x, c4.x, fmaf(uv[i].y, c4.y, fmaf(uv[i].z, c4.z, fmaf(uv[i].w, c4.w, pc))));
    }

    // lse_c from 8 partials
    float M = -1e30f, SSm = 0.f;
#pragma unroll
    for (int p = 0; p < 8; ++p) {
        float m2 = partm[u * 8 + p], s2 = parts[u * 8 + p];
        if (s2 > 0.f) {
            if (m2 <= M) SSm += s2 * __expf(m2 - M);
            else { SSm = SSm * __expf(M - m2) + s2; M = m2; }
        }
    }
    float lse_c = M + logf(SSm);

    // job loss: 100 rel rows
    float mj = -1e30f, sj = 0.f;
    for (int j = 0; j < 100; ++j) {
        const float4* rj = (const float4*)(rel + (size_t)j * DD);
        float dj = 0.f;
#pragma unroll
        for (int i = 0; i < 32; ++i) {
            float4 r4 = rj[i];
            dj = fmaf(uv[i].x, r4.x, fmaf(uv[i].y, r4.y, fmaf(uv[i].z, r4.z, fmaf(uv[i].w, r4.w, dj))));
        }
        lse_push(dj, mj, sj);
    }
    float lse_j = mj + logf(sj);

    const float4* tj = (const float4*)(rel + (size_t)jt[u] * DD);
    float pj = 0.f;
#pragma unroll
    for (int i = 0; i < 32; ++i) {
        float4 r4 = tj[i];
        pj = fmaf(uv[i].x, r4.x, fmaf(uv[i].y, r4.y, fmaf(uv[i].z, r4.z, fmaf(uv[i].w, r4.w, pj))));
    }

    atomicAdd(&out[0], lse_c - pc);
    atomicAdd(&out[1], lse_j - pj);
}

// ---------------- host ----------------
extern "C" void kernel_launch(void* const* d_in, const int* in_sizes, int n_in,
                              void* d_out, int out_size, void* d_ws, size_t ws_size,
                              hipStream_t stream) {
    const float* ent_emb = (const float*)d_in[0];
    const float* c0_emb  = (const float*)d_in[1];
    const float* rel_emb = (const float*)d_in[2];
    const float* W_ih    = (const float*)d_in[3];
    const float* W_hh    = (const float*)d_in[4];
    const float* b_ih    = (const float*)d_in[5];
    const float* b_hh    = (const float*)d_in[6];
    const int* src       = (const int*)d_in[7];
    const int* dst       = (const int*)d_in[8];
    const int* rel_idx   = (const int*)d_in[9];
    const int* seed_idx  = (const int*)d_in[10];
    const int* ubatch    = (const int*)d_in[11];
    const int* ctarg     = (const int*)d_in[12];
    const int* jtarg     = (const int*)d_in[13];
    float* out = (float*)d_out;

    const size_t HB = (size_t)ENTITY_NUM_ * DD * sizeof(float);  // 76,801,024
    char* p = (char*)d_ws;
    float* h0   = (float*)(p);
    float* h1   = (float*)(p + HB);
    float* cbuf = (float*)(p + 2 * HB);
    int*   cnt  = (int*)  (p + 3 * HB);
    float* invp = (float*)(p + 3 * HB + 600064);
    short* Wt   = (short*)(p + 3 * HB + 2 * 600064);
    float* bsum = (float*)(p + 3 * HB + 2 * 600064 + 262144);
    float* partm= (float*)(p + 3 * HB + 2 * 600064 + 262144 + 2048);
    float* parts= (float*)(p + 3 * HB + 2 * 600064 + 262144 + 2048 + 32768);

    hipMemsetAsync(d_out, 0, 2 * sizeof(float), stream);

    const int n4 = ENTITY_NUM_ * DD / 4;            // 4,800,064
    const int gcpy = (n4 + 255) / 256;              // 18751
    copy4_k<<<gcpy, 256, 0, stream>>>((float4*)h0, (const float4*)ent_emb, n4);
    copy4_k<<<gcpy, 256, 0, stream>>>((float4*)cbuf, (const float4*)c0_emb, n4);
    prepW_k<<<512, 256, 0, stream>>>(W_ih, W_hh, b_ih, b_hh, Wt, bsum);

    float* hold = h0;
    float* hnew = h1;
    const int gz = (ENTITY_NUM_ + 255) / 256;       // 587
    const int gh = (EE + 255) / 256;                // 977

    for (int t = 0; t < TT; ++t) {
        const int* srcT = src + (size_t)t * EE;
        const int* dstT = dst + (size_t)t * EE;
        const int* relT = rel_idx + (size_t)t * EE;
        const int* seedT = seed_idx + (size_t)t * SS;

        zero_i32_k<<<gz, 256, 0, stream>>>(cnt, ENTITY_NUM_);
        hist_k<<<gh, 256, 0, stream>>>(cnt, dstT, EE);
        inv_k<<<gz, 256, 0, stream>>>(cnt, invp, ENTITY_NUM_);
        copy4_k<<<gcpy, 256, 0, stream>>>((float4*)hnew, (const float4*)hold, n4);
        scatter_k<<<EE * 128 / 256, 256, 0, stream>>>(hold, hnew, rel_emb, invp, srcT, dstT, relT);
        lstm_k<<<SS / 32, 256, 0, stream>>>(hold, hnew, cbuf, Wt, bsum, seedT);

        float* tmp = hold; hold = hnew; hnew = tmp;
    }

    // hold == final h
    comp_partial_k<<<dim3(64, 8), 256, 0, stream>>>(hold, ent_emb, ubatch, partm, parts);
    finish_k<<<4, 256, 0, stream>>>(hold, ent_emb, rel_emb, ubatch, ctarg, jtarg, partm, parts, out);
}

// Round 2
// 2378.012 us; speedup vs baseline: 1.2565x; 1.2565x over previous
//
#include <hip/hip_runtime.h>
#include <math.h>

typedef __attribute__((ext_vector_type(8))) short short8;
typedef __attribute__((ext_vector_type(4))) float f32x4;

#define USER_NUM_  100000
#define COMP_NUM_  50000
#define EN         150002
#define ENP        (EN + 1)
#define REL_NUM_   200
#define DD         128
#define TT         12
#define EE         250000
#define SS         20000
#define BB         1024
#define NBLK       587      // ceil(EN/256)
#define PPART      125      // comp partitions
#define TILES_PP   25       // 16-comp tiles per partition (125*25*16 = 50000)

__device__ inline short f2bf(float f) {
    unsigned u = __float_as_uint(f);
    unsigned r = (u + 0x7fffu + ((u >> 16) & 1u)) >> 16;
    return (short)r;
}

__device__ inline short8 pack_bf8(float4 a, float4 b) {
    short8 r;
    r[0] = f2bf(a.x); r[1] = f2bf(a.y); r[2] = f2bf(a.z); r[3] = f2bf(a.w);
    r[4] = f2bf(b.x); r[5] = f2bf(b.y); r[6] = f2bf(b.z); r[7] = f2bf(b.w);
    return r;
}

__device__ inline float sigmoidf_(float x) { return 1.f / (1.f + __expf(-x)); }

__device__ inline void lse_push(float v, float& m, float& s) {
    if (v <= m) { s += __expf(v - m); }
    else { s = s * __expf(m - v) + 1.f; m = v; }
}

// ---------------- utility ----------------
__global__ __launch_bounds__(256) void copy4_k(float4* __restrict__ dst, const float4* __restrict__ src, int n4) {
    int i = blockIdx.x * 256 + threadIdx.x;
    if (i < n4) dst[i] = src[i];
}

__global__ __launch_bounds__(256) void zero_i32_k(int* __restrict__ p, int n) {
    int i = blockIdx.x * 256 + threadIdx.x;
    if (i < n) p[i] = 0;
}

__global__ __launch_bounds__(256) void prepW_k(const float* __restrict__ Wih, const float* __restrict__ Whh,
                                               const float* __restrict__ bih, const float* __restrict__ bhh,
                                               short* __restrict__ Wt, float* __restrict__ bsum) {
    int n = blockIdx.x;      // 0..511
    int k = threadIdx.x;     // 0..255
    float v = (k < 128) ? Wih[n * 128 + k] : Whh[n * 128 + (k - 128)];
    Wt[n * 256 + k] = f2bf(v);
    if (k == 0) bsum[n] = bih[n] + bhh[n];
}

// ---------------- CSR build (NT steps at once via blockIdx.y) ----------------
__global__ __launch_bounds__(256) void hist_k(int* __restrict__ cnt, const int* __restrict__ dst, int t0) {
    int slot = blockIdx.y;
    int e = blockIdx.x * 256 + threadIdx.x;
    if (e < EE) atomicAdd(&cnt[slot * EN + dst[(size_t)(t0 + slot) * EE + e]], 1);
}

__global__ __launch_bounds__(256) void scanA_k(const int* __restrict__ cnt, int* __restrict__ incl,
                                               int* __restrict__ bsums) {
    int slot = blockIdx.y;
    int tid = threadIdx.x;
    int i = blockIdx.x * 256 + tid;
    int v = (i < EN) ? cnt[slot * EN + i] : 0;
    __shared__ int lds[256];
    lds[tid] = v; __syncthreads();
#pragma unroll
    for (int o = 1; o < 256; o <<= 1) {
        int x = (tid >= o) ? lds[tid - o] : 0;
        __syncthreads();
        lds[tid] += x;
        __syncthreads();
    }
    int vin = lds[tid];
    if (i < EN) incl[slot * EN + i] = vin;
    if (tid == 255) bsums[slot * NBLK + blockIdx.x] = vin;
}

__global__ __launch_bounds__(1024) void scanB_k(int* __restrict__ bsums) {
    int slot = blockIdx.x;
    int tid = threadIdx.x;
    int v = (tid < NBLK) ? bsums[slot * NBLK + tid] : 0;
    __shared__ int lds[1024];
    lds[tid] = v; __syncthreads();
#pragma unroll
    for (int o = 1; o < 1024; o <<= 1) {
        int x = (tid >= o) ? lds[tid - o] : 0;
        __syncthreads();
        lds[tid] += x;
        __syncthreads();
    }
    if (tid < NBLK) bsums[slot * NBLK + tid] = lds[tid] - v;  // exclusive
}

__global__ __launch_bounds__(256) void scanC_k(const int* __restrict__ cnt, const int* __restrict__ incl,
                                               const int* __restrict__ bsums, int* __restrict__ off,
                                               int* __restrict__ cur) {
    int slot = blockIdx.y;
    int i = blockIdx.x * 256 + threadIdx.x;
    if (i >= EN) return;
    int c = cnt[slot * EN + i];
    int ex = incl[slot * EN + i] - c + bsums[slot * NBLK + blockIdx.x];
    off[slot * ENP + i] = ex;
    cur[slot * EN + i] = ex;
    if (i == EN - 1) off[slot * ENP + EN] = ex + c;
}

__global__ __launch_bounds__(256) void reorder_k(const int* __restrict__ src, const int* __restrict__ dst,
                                                 const int* __restrict__ rel, int* __restrict__ cur,
                                                 int* __restrict__ pairs, int t0) {
    int slot = blockIdx.y;
    int e = blockIdx.x * 256 + threadIdx.x;
    if (e >= EE) return;
    size_t gi = (size_t)(t0 + slot) * EE + e;
    int d = dst[gi];
    int pos = atomicAdd(&cur[slot * EN + d], 1);
    pairs[(size_t)slot * EE + pos] = src[gi] | (rel[gi] << 18);
}

// ---------------- fused aggregate: x[d] = h[d] + (1/cnt)*sum h[src]*rel[r] ----------------
__global__ __launch_bounds__(256) void agg_k(const float* __restrict__ hold, float* __restrict__ hnew,
                                             const float* __restrict__ relemb, const int* __restrict__ off,
                                             const int* __restrict__ pairs, int slot) {
    int tid = threadIdx.x;
    int d = blockIdx.x * 2 + (tid >> 7);
    int k = tid & 127;
    if (d >= EN) return;
    const int* offp = off + (size_t)slot * ENP;
    int e0 = offp[d], e1 = offp[d + 1];
    const int* pp = pairs + (size_t)slot * EE;
    float m = 0.f;
    for (int e = e0; e < e1; ++e) {
        int pk = pp[e];
        int s = pk & 0x3FFFF;
        int r = pk >> 18;
        m = fmaf(hold[(size_t)s * DD + k], relemb[r * DD + k], m);
    }
    float h = hold[(size_t)d * DD + k];
    int c = e1 - e0;
    hnew[(size_t)d * DD + k] = (c > 0) ? fmaf(m, 1.f / (float)c, h) : h;
}

// ---------------- LSTM on seed rows (MFMA bf16) ----------------
__global__ __launch_bounds__(256) void lstm_k(const float* __restrict__ hold, float* __restrict__ hnew,
                                              float* __restrict__ cbuf, const short* __restrict__ Wt,
                                              const float* __restrict__ bsum, const int* __restrict__ seed) {
    int w = threadIdx.x >> 6;
    int lane = threadIdx.x & 63;
    int lrow = lane & 15, lhi = lane >> 4;
    int m0 = blockIdx.x * 32;
    int w32 = w * 32;

    const float* pxi[2];
    const float* php[2];
#pragma unroll
    for (int mi = 0; mi < 2; ++mi) {
        int m = m0 + mi * 16 + lrow;
        int sd = seed[m];
        pxi[mi] = hnew + (size_t)sd * DD;
        php[mi] = hold + (size_t)sd * DD;
    }

    f32x4 acc[2][4][2];
#pragma unroll
    for (int mi = 0; mi < 2; ++mi)
#pragma unroll
        for (int g = 0; g < 4; ++g)
#pragma unroll
            for (int s = 0; s < 2; ++s)
                acc[mi][g][s] = (f32x4){0.f, 0.f, 0.f, 0.f};

#pragma unroll
    for (int kk = 0; kk < 8; ++kk) {
        int klane = kk * 32 + lhi * 8;
        short8 af[2];
#pragma unroll
        for (int mi = 0; mi < 2; ++mi) {
            const float* p = (klane < 128) ? (pxi[mi] + klane) : (php[mi] + (klane - 128));
            float4 a = *(const float4*)p;
            float4 b = *(const float4*)(p + 4);
            af[mi] = pack_bf8(a, b);
        }
#pragma unroll
        for (int g = 0; g < 4; ++g)
#pragma unroll
            for (int s = 0; s < 2; ++s) {
                int col = g * 128 + w32 + s * 16 + lrow;
                short8 bf = *(const short8*)(Wt + col * 256 + klane);
                acc[0][g][s] = __builtin_amdgcn_mfma_f32_16x16x32_bf16(af[0], bf, acc[0][g][s], 0, 0, 0);
                acc[1][g][s] = __builtin_amdgcn_mfma_f32_16x16x32_bf16(af[1], bf, acc[1][g][s], 0, 0, 0);
            }
    }

    __syncthreads();

#pragma unroll
    for (int mi = 0; mi < 2; ++mi) {
#pragma unroll
        for (int r = 0; r < 4; ++r) {
            int m = m0 + mi * 16 + lhi * 4 + r;
            int sd = seed[m];
#pragma unroll
            for (int s = 0; s < 2; ++s) {
                int d = w32 + s * 16 + lrow;
                float ig = acc[mi][0][s][r] + bsum[d];
                float fg = acc[mi][1][s][r] + bsum[128 + d];
                float gg = acc[mi][2][s][r] + bsum[256 + d];
                float og = acc[mi][3][s][r] + bsum[384 + d];
                float cp = cbuf[(size_t)sd * DD + d];
                float cn = sigmoidf_(fg) * cp + sigmoidf_(ig) * tanhf(gg);
                float hn = sigmoidf_(og) * tanhf(cn);
                cbuf[(size_t)sd * DD + d] = cn;
                hnew[(size_t)sd * DD + d] = hn;
            }
        }
    }
}

// ---------------- comp loss: bf16 packers ----------------
__global__ __launch_bounds__(256) void packC_k(const float* __restrict__ ent, short* __restrict__ Cbf) {
    int i4 = blockIdx.x * 256 + threadIdx.x;   // over 50000*128/4 = 1,600,000
    if (i4 >= COMP_NUM_ * DD / 4) return;
    float4 v = ((const float4*)(ent + (size_t)USER_NUM_ * DD))[i4];
    short* o = Cbf + (size_t)i4 * 4;
    o[0] = f2bf(v.x); o[1] = f2bf(v.y); o[2] = f2bf(v.z); o[3] = f2bf(v.w);
}

__global__ __launch_bounds__(256) void packU_k(const float* __restrict__ hfin, const int* __restrict__ ub,
                                               short* __restrict__ Ubf) {
    int i = blockIdx.x * 256 + threadIdx.x;    // over 1024*128
    if (i >= BB * DD) return;
    int u = i >> 7, k = i & 127;
    Ubf[i] = f2bf(hfin[(size_t)ub[u] * DD + k]);
}

// ---------------- comp loss: MFMA GEMM + per-lane online LSE ----------------
// grid (8 ublocks, 125 partitions), 256 threads = 4 waves; wave handles 32 users (2 A-frag sets).
__global__ __launch_bounds__(256) void comp_mfma_k(const short* __restrict__ Ubf, const short* __restrict__ Cbf,
                                                   float* __restrict__ partm, float* __restrict__ parts) {
    int w = threadIdx.x >> 6, lane = threadIdx.x & 63;
    int lrow = lane & 15, lhi = lane >> 4;
    int ubase = blockIdx.x * 128 + w * 32;
    int p = blockIdx.y;

    short8 a[2][4];
#pragma unroll
    for (int s2 = 0; s2 < 2; ++s2)
#pragma unroll
        for (int kc = 0; kc < 4; ++kc)
            a[s2][kc] = *(const short8*)(Ubf + (size_t)(ubase + s2 * 16 + lrow) * DD + kc * 32 + lhi * 8);

    float m[2][4], s[2][4];
#pragma unroll
    for (int s2 = 0; s2 < 2; ++s2)
#pragma unroll
        for (int r = 0; r < 4; ++r) { m[s2][r] = -1e30f; s[s2][r] = 0.f; }

    int c0 = p * TILES_PP * 16;
    for (int tile = 0; tile < TILES_PP; ++tile) {
        int comp = c0 + tile * 16 + lrow;
        f32x4 acc0 = {0.f, 0.f, 0.f, 0.f};
        f32x4 acc1 = {0.f, 0.f, 0.f, 0.f};
#pragma unroll
        for (int kc = 0; kc < 4; ++kc) {
            short8 b = *(const short8*)(Cbf + (size_t)comp * DD + kc * 32 + lhi * 8);
            acc0 = __builtin_amdgcn_mfma_f32_16x16x32_bf16(a[0][kc], b, acc0, 0, 0, 0);
            acc1 = __builtin_amdgcn_mfma_f32_16x16x32_bf16(a[1][kc], b, acc1, 0, 0, 0);
        }
#pragma unroll
        for (int r = 0; r < 4; ++r) {
            lse_push(acc0[r], m[0][r], s[0][r]);
            lse_push(acc1[r], m[1][r], s[1][r]);
        }
    }

#pragma unroll
    for (int s2 = 0; s2 < 2; ++s2)
#pragma unroll
        for (int r = 0; r < 4; ++r) {
            float M = m[s2][r], S = s[s2][r];
#pragma unroll
            for (int o = 1; o < 16; o <<= 1) {
                float M2 = __shfl_xor(M, o, 64);
                float S2 = __shfl_xor(S, o, 64);
                if (M2 > M) { S = S * __expf(M - M2) + S2; M = M2; }
                else { S += S2 * __expf(M2 - M); }
            }
            if (lrow == 0) {
                int u = ubase + s2 * 16 + lhi * 4 + r;
                partm[(size_t)u * PPART + p] = M;
                parts[(size_t)u * PPART + p] = S;
            }
        }
}

// ---------------- finish ----------------
__global__ __launch_bounds__(256) void finish_k(const float* __restrict__ hfin, const float* __restrict__ ent,
                                                const float* __restrict__ rel, const int* __restrict__ ub,
                                                const int* __restrict__ ct, const int* __restrict__ jt,
                                                const float* __restrict__ partm, const float* __restrict__ parts,
                                                float* __restrict__ out) {
    int u = blockIdx.x * 256 + threadIdx.x;
    if (u >= BB) return;

    const float4* uvp = (const float4*)(hfin + (size_t)ub[u] * DD);
    float4 uv[32];
#pragma unroll
    for (int i = 0; i < 32; ++i) uv[i] = uvp[i];

    const float4* tc = (const float4*)(ent + (size_t)(USER_NUM_ + ct[u]) * DD);
    float pc = 0.f;
#pragma unroll
    for (int i = 0; i < 32; ++i) {
        float4 c4 = tc[i];
        pc = fmaf(uv[i].x, c4.x, fmaf(uv[i].y, c4.y, fmaf(uv[i].z, c4.z, fmaf(uv[i].w, c4.w, pc))));
    }

    float M = -1e30f, SSm = 0.f;
    for (int p = 0; p < PPART; ++p) {
        float m2 = partm[(size_t)u * PPART + p], s2 = parts[(size_t)u * PPART + p];
        if (s2 > 0.f) {
            if (m2 <= M) SSm += s2 * __expf(m2 - M);
            else { SSm = SSm * __expf(M - m2) + s2; M = m2; }
        }
    }
    float lse_c = M + logf(SSm);

    float mj = -1e30f, sj = 0.f;
    for (int j = 0; j < 100; ++j) {
        const float4* rj = (const float4*)(rel + (size_t)j * DD);
        float dj = 0.f;
#pragma unroll
        for (int i = 0; i < 32; ++i) {
            float4 r4 = rj[i];
            dj = fmaf(uv[i].x, r4.x, fmaf(uv[i].y, r4.y, fmaf(uv[i].z, r4.z, fmaf(uv[i].w, r4.w, dj))));
        }
        lse_push(dj, mj, sj);
    }
    float lse_j = mj + logf(sj);

    const float4* tjp = (const float4*)(rel + (size_t)jt[u] * DD);
    float pj = 0.f;
#pragma unroll
    for (int i = 0; i < 32; ++i) {
        float4 r4 = tjp[i];
        pj = fmaf(uv[i].x, r4.x, fmaf(uv[i].y, r4.y, fmaf(uv[i].z, r4.z, fmaf(uv[i].w, r4.w, pj))));
    }

    atomicAdd(&out[0], lse_c - pc);
    atomicAdd(&out[1], lse_j - pj);
}

// ---------------- host ----------------
static inline size_t rup(size_t x) { return (x + 255) & ~(size_t)255; }

extern "C" void kernel_launch(void* const* d_in, const int* in_sizes, int n_in,
                              void* d_out, int out_size, void* d_ws, size_t ws_size,
                              hipStream_t stream) {
    const float* ent_emb = (const float*)d_in[0];
    const float* c0_emb  = (const float*)d_in[1];
    const float* rel_emb = (const float*)d_in[2];
    const float* W_ih    = (const float*)d_in[3];
    const float* W_hh    = (const float*)d_in[4];
    const float* b_ih    = (const float*)d_in[5];
    const float* b_hh    = (const float*)d_in[6];
    const int* src       = (const int*)d_in[7];
    const int* dst       = (const int*)d_in[8];
    const int* rel_idx   = (const int*)d_in[9];
    const int* seed_idx  = (const int*)d_in[10];
    const int* ubatch    = (const int*)d_in[11];
    const int* ctarg     = (const int*)d_in[12];
    const int* jtarg     = (const int*)d_in[13];
    float* out = (float*)d_out;

    const size_t HB = (size_t)EN * DD * sizeof(float);   // 76,801,024

    // layout helper: returns total size for NT, sets pointers
    char* base = (char*)d_ws;
    float* h0 = (float*)base;
    float* h1 = (float*)(base + HB);
    float* cbuf = (float*)(base + 2 * HB);

    auto place = [&](int NT, int** off, int** pairs, int** cnt, int** incl, int** cur,
                     int** bsums, short** Wt, float** bsumv) -> size_t {
        size_t o = 3 * HB;
        *off   = (int*)(base + o); o += rup((size_t)NT * ENP * 4);
        *pairs = (int*)(base + o); o += rup((size_t)NT * EE * 4);
        *cnt   = (int*)(base + o); o += rup((size_t)NT * EN * 4);
        *incl  = (int*)(base + o); o += rup((size_t)NT * EN * 4);
        *cur   = (int*)(base + o); o += rup((size_t)NT * EN * 4);
        *bsums = (int*)(base + o); o += rup((size_t)NT * NBLK * 4);
        *Wt    = (short*)(base + o); o += rup(512 * 256 * 2);
        *bsumv = (float*)(base + o); o += rup(512 * 4);
        return o;
    };

    int *off, *pairs, *cnt, *incl, *cur, *bsums;
    short* Wt; float* bsumv;
    size_t need12 = place(TT, &off, &pairs, &cnt, &incl, &cur, &bsums, &Wt, &bsumv);
    int NT = (ws_size >= need12) ? TT : 1;
    if (NT != TT) place(1, &off, &pairs, &cnt, &incl, &cur, &bsums, &Wt, &bsumv);

    // comp-phase buffers alias cbuf region (dead after step loop)
    char* q = (char*)cbuf;
    short* Cbf = (short*)q;            q += rup((size_t)COMP_NUM_ * DD * 2);  // 12.8 MB
    short* Ubf = (short*)q;            q += rup((size_t)BB * DD * 2);
    float* partm = (float*)q;          q += rup((size_t)BB * PPART * 4);
    float* parts = (float*)q;

    hipMemsetAsync(d_out, 0, 2 * sizeof(float), stream);

    const int n4 = EN * DD / 4;
    const int gcpy = (n4 + 255) / 256;
    const int ge = (EE + 255) / 256;

    prepW_k<<<512, 256, 0, stream>>>(W_ih, W_hh, b_ih, b_hh, Wt, bsumv);
    copy4_k<<<gcpy, 256, 0, stream>>>((float4*)h0, (const float4*)ent_emb, n4);
    copy4_k<<<gcpy, 256, 0, stream>>>((float4*)cbuf, (const float4*)c0_emb, n4);

    auto build = [&](int t0, int nt) {
        zero_i32_k<<<(nt * EN + 255) / 256, 256, 0, stream>>>(cnt, nt * EN);
        hist_k<<<dim3(ge, nt), 256, 0, stream>>>(cnt, dst, t0);
        scanA_k<<<dim3(NBLK, nt), 256, 0, stream>>>(cnt, incl, bsums);
        scanB_k<<<nt, 1024, 0, stream>>>(bsums);
        scanC_k<<<dim3(NBLK, nt), 256, 0, stream>>>(cnt, incl, bsums, off, cur);
        reorder_k<<<dim3(ge, nt), 256, 0, stream>>>(src, dst, rel_idx, cur, pairs, t0);
    };

    if (NT == TT) build(0, TT);

    float* hold = h0;
    float* hnew = h1;
    const int gagg = (EN + 1) / 2;

    for (int t = 0; t < TT; ++t) {
        if (NT == 1) build(t, 1);
        int slot = (NT == TT) ? t : 0;
        agg_k<<<gagg, 256, 0, stream>>>(hold, hnew, rel_emb, off, pairs, slot);
        lstm_k<<<SS / 32, 256, 0, stream>>>(hold, hnew, cbuf, Wt, bsumv, seed_idx + (size_t)t * SS);
        float* tmp = hold; hold = hnew; hnew = tmp;
    }

    // NOTE: cbuf region is reused for Cbf/Ubf/partials from here on
    packC_k<<<(COMP_NUM_ * DD / 4 + 255) / 256, 256, 0, stream>>>(ent_emb, Cbf);
    packU_k<<<(BB * DD + 255) / 256, 256, 0, stream>>>(hold, ubatch, Ubf);
    comp_mfma_k<<<dim3(BB / 128, PPART), 256, 0, stream>>>(Ubf, Cbf, partm, parts);
    finish_k<<<(BB + 255) / 256, 256, 0, stream>>>(hold, ent_emb, rel_emb, ubatch, ctarg, jtarg,
                                                   partm, parts, out);
}

// Round 3
// 2086.955 us; speedup vs baseline: 1.4317x; 1.1395x over previous
//
#include <hip/hip_runtime.h>
#include <math.h>

typedef __attribute__((ext_vector_type(8))) short short8;
typedef __attribute__((ext_vector_type(4))) float f32x4;

#define USER_NUM_  100000
#define COMP_NUM_  50000
#define EN         150002
#define ENP        (EN + 1)
#define REL_NUM_   200
#define DD         128
#define TT         12
#define EE         250000
#define SS         20000
#define BB         1024
#define NBLK       587      // ceil(EN/256)
#define PPART      125      // comp partitions
#define TILES_PP   25       // 16-comp tiles per partition (125*25*16 = 50000)

__device__ inline short f2bf(float f) {
    unsigned u = __float_as_uint(f);
    unsigned r = (u + 0x7fffu + ((u >> 16) & 1u)) >> 16;
    return (short)r;
}

__device__ inline short8 pack_bf8(float4 a, float4 b) {
    short8 r;
    r[0] = f2bf(a.x); r[1] = f2bf(a.y); r[2] = f2bf(a.z); r[3] = f2bf(a.w);
    r[4] = f2bf(b.x); r[5] = f2bf(b.y); r[6] = f2bf(b.z); r[7] = f2bf(b.w);
    return r;
}

__device__ inline float sigmoidf_(float x) { return 1.f / (1.f + __expf(-x)); }

__device__ inline void lse_push(float v, float& m, float& s) {
    if (v <= m) { s += __expf(v - m); }
    else { s = s * __expf(m - v) + 1.f; m = v; }
}

__device__ inline void lse_merge(float& M, float& S, float M2, float S2) {
    float Mn = fmaxf(M, M2);
    S = S * __expf(M - Mn) + S2 * __expf(M2 - Mn);
    M = Mn;
}

// ---------------- utility ----------------
__global__ __launch_bounds__(256) void copy4_k(float4* __restrict__ dst, const float4* __restrict__ src, int n4) {
    int i = blockIdx.x * 256 + threadIdx.x;
    if (i < n4) dst[i] = src[i];
}

__global__ __launch_bounds__(256) void zero_i32_k(int* __restrict__ p, int n) {
    int i = blockIdx.x * 256 + threadIdx.x;
    if (i < n) p[i] = 0;
}

__global__ __launch_bounds__(256) void prepW_k(const float* __restrict__ Wih, const float* __restrict__ Whh,
                                               const float* __restrict__ bih, const float* __restrict__ bhh,
                                               short* __restrict__ Wt, float* __restrict__ bsum) {
    int n = blockIdx.x;      // 0..511
    int k = threadIdx.x;     // 0..255
    float v = (k < 128) ? Wih[n * 128 + k] : Whh[n * 128 + (k - 128)];
    Wt[n * 256 + k] = f2bf(v);
    if (k == 0) bsum[n] = bih[n] + bhh[n];
}

// ---------------- CSR build (NT steps at once via blockIdx.y) ----------------
__global__ __launch_bounds__(256) void hist_k(int* __restrict__ cnt, const int* __restrict__ dst, int t0) {
    int slot = blockIdx.y;
    int e = blockIdx.x * 256 + threadIdx.x;
    if (e < EE) atomicAdd(&cnt[slot * EN + dst[(size_t)(t0 + slot) * EE + e]], 1);
}

__global__ __launch_bounds__(256) void scanA_k(const int* __restrict__ cnt, int* __restrict__ incl,
                                               int* __restrict__ bsums) {
    int slot = blockIdx.y;
    int tid = threadIdx.x;
    int i = blockIdx.x * 256 + tid;
    int v = (i < EN) ? cnt[slot * EN + i] : 0;
    __shared__ int lds[256];
    lds[tid] = v; __syncthreads();
#pragma unroll
    for (int o = 1; o < 256; o <<= 1) {
        int x = (tid >= o) ? lds[tid - o] : 0;
        __syncthreads();
        lds[tid] += x;
        __syncthreads();
    }
    int vin = lds[tid];
    if (i < EN) incl[slot * EN + i] = vin;
    if (tid == 255) bsums[slot * NBLK + blockIdx.x] = vin;
}

__global__ __launch_bounds__(1024) void scanB_k(int* __restrict__ bsums) {
    int slot = blockIdx.x;
    int tid = threadIdx.x;
    int v = (tid < NBLK) ? bsums[slot * NBLK + tid] : 0;
    __shared__ int lds[1024];
    lds[tid] = v; __syncthreads();
#pragma unroll
    for (int o = 1; o < 1024; o <<= 1) {
        int x = (tid >= o) ? lds[tid - o] : 0;
        __syncthreads();
        lds[tid] += x;
        __syncthreads();
    }
    if (tid < NBLK) bsums[slot * NBLK + tid] = lds[tid] - v;  // exclusive
}

__global__ __launch_bounds__(256) void scanC_k(const int* __restrict__ cnt, const int* __restrict__ incl,
                                               const int* __restrict__ bsums, int* __restrict__ off,
                                               int* __restrict__ cur) {
    int slot = blockIdx.y;
    int i = blockIdx.x * 256 + threadIdx.x;
    if (i >= EN) return;
    int c = cnt[slot * EN + i];
    int ex = incl[slot * EN + i] - c + bsums[slot * NBLK + blockIdx.x];
    off[slot * ENP + i] = ex;
    cur[slot * EN + i] = ex;
    if (i == EN - 1) off[slot * ENP + EN] = ex + c;
}

__global__ __launch_bounds__(256) void reorder_k(const int* __restrict__ src, const int* __restrict__ dst,
                                                 const int* __restrict__ rel, int* __restrict__ cur,
                                                 int* __restrict__ pairs, int t0) {
    int slot = blockIdx.y;
    int e = blockIdx.x * 256 + threadIdx.x;
    if (e >= EE) return;
    size_t gi = (size_t)(t0 + slot) * EE + e;
    int d = dst[gi];
    int pos = atomicAdd(&cur[slot * EN + d], 1);
    pairs[(size_t)slot * EE + pos] = src[gi] | (rel[gi] << 18);
}

// ---------------- fused aggregate: x[d] = h[d] + (1/cnt)*sum h[src]*rel[r] ----------------
__global__ __launch_bounds__(256) void agg_k(const float* __restrict__ hold, float* __restrict__ hnew,
                                             const float* __restrict__ relemb, const int* __restrict__ off,
                                             const int* __restrict__ pairs, int slot) {
    int tid = threadIdx.x;
    int d = blockIdx.x * 2 + (tid >> 7);
    int k = tid & 127;
    if (d >= EN) return;
    const int* offp = off + (size_t)slot * ENP;
    int e0 = offp[d], e1 = offp[d + 1];
    const int* pp = pairs + (size_t)slot * EE;
    float m = 0.f;
    for (int e = e0; e < e1; ++e) {
        int pk = pp[e];
        int s = pk & 0x3FFFF;
        int r = pk >> 18;
        m = fmaf(hold[(size_t)s * DD + k], relemb[r * DD + k], m);
    }
    float h = hold[(size_t)d * DD + k];
    int c = e1 - e0;
    hnew[(size_t)d * DD + k] = (c > 0) ? fmaf(m, 1.f / (float)c, h) : h;
}

// ---------------- LSTM on seed rows (MFMA bf16) ----------------
__global__ __launch_bounds__(256) void lstm_k(const float* __restrict__ hold, float* __restrict__ hnew,
                                              float* __restrict__ cbuf, const short* __restrict__ Wt,
                                              const float* __restrict__ bsum, const int* __restrict__ seed) {
    int w = threadIdx.x >> 6;
    int lane = threadIdx.x & 63;
    int lrow = lane & 15, lhi = lane >> 4;
    int m0 = blockIdx.x * 32;
    int w32 = w * 32;

    const float* pxi[2];
    const float* php[2];
#pragma unroll
    for (int mi = 0; mi < 2; ++mi) {
        int m = m0 + mi * 16 + lrow;
        int sd = seed[m];
        pxi[mi] = hnew + (size_t)sd * DD;
        php[mi] = hold + (size_t)sd * DD;
    }

    f32x4 acc[2][4][2];
#pragma unroll
    for (int mi = 0; mi < 2; ++mi)
#pragma unroll
        for (int g = 0; g < 4; ++g)
#pragma unroll
            for (int s = 0; s < 2; ++s)
                acc[mi][g][s] = (f32x4){0.f, 0.f, 0.f, 0.f};

#pragma unroll
    for (int kk = 0; kk < 8; ++kk) {
        int klane = kk * 32 + lhi * 8;
        short8 af[2];
#pragma unroll
        for (int mi = 0; mi < 2; ++mi) {
            const float* p = (klane < 128) ? (pxi[mi] + klane) : (php[mi] + (klane - 128));
            float4 a = *(const float4*)p;
            float4 b = *(const float4*)(p + 4);
            af[mi] = pack_bf8(a, b);
        }
#pragma unroll
        for (int g = 0; g < 4; ++g)
#pragma unroll
            for (int s = 0; s < 2; ++s) {
                int col = g * 128 + w32 + s * 16 + lrow;
                short8 bf = *(const short8*)(Wt + col * 256 + klane);
                acc[0][g][s] = __builtin_amdgcn_mfma_f32_16x16x32_bf16(af[0], bf, acc[0][g][s], 0, 0, 0);
                acc[1][g][s] = __builtin_amdgcn_mfma_f32_16x16x32_bf16(af[1], bf, acc[1][g][s], 0, 0, 0);
            }
    }

    __syncthreads();

#pragma unroll
    for (int mi = 0; mi < 2; ++mi) {
#pragma unroll
        for (int r = 0; r < 4; ++r) {
            int m = m0 + mi * 16 + lhi * 4 + r;
            int sd = seed[m];
#pragma unroll
            for (int s = 0; s < 2; ++s) {
                int d = w32 + s * 16 + lrow;
                float ig = acc[mi][0][s][r] + bsum[d];
                float fg = acc[mi][1][s][r] + bsum[128 + d];
                float gg = acc[mi][2][s][r] + bsum[256 + d];
                float og = acc[mi][3][s][r] + bsum[384 + d];
                float cp = cbuf[(size_t)sd * DD + d];
                float cn = sigmoidf_(fg) * cp + sigmoidf_(ig) * tanhf(gg);
                float hn = sigmoidf_(og) * tanhf(cn);
                cbuf[(size_t)sd * DD + d] = cn;
                hnew[(size_t)sd * DD + d] = hn;
            }
        }
    }
}

// ---------------- comp loss: bf16 packers ----------------
__global__ __launch_bounds__(256) void packC_k(const float* __restrict__ ent, short* __restrict__ Cbf) {
    int i4 = blockIdx.x * 256 + threadIdx.x;   // over 50000*128/4 = 1,600,000
    if (i4 >= COMP_NUM_ * DD / 4) return;
    float4 v = ((const float4*)(ent + (size_t)USER_NUM_ * DD))[i4];
    short* o = Cbf + (size_t)i4 * 4;
    o[0] = f2bf(v.x); o[1] = f2bf(v.y); o[2] = f2bf(v.z); o[3] = f2bf(v.w);
}

__global__ __launch_bounds__(256) void packU_k(const float* __restrict__ hfin, const int* __restrict__ ub,
                                               short* __restrict__ Ubf) {
    int i = blockIdx.x * 256 + threadIdx.x;    // over 1024*128
    if (i >= BB * DD) return;
    int u = i >> 7, k = i & 127;
    Ubf[i] = f2bf(hfin[(size_t)ub[u] * DD + k]);
}

// ---------------- comp loss: MFMA GEMM + per-lane online LSE ----------------
// grid (8 ublocks, 125 partitions), 256 threads = 4 waves; wave handles 32 users (2 A-frag sets).
__global__ __launch_bounds__(256) void comp_mfma_k(const short* __restrict__ Ubf, const short* __restrict__ Cbf,
                                                   float* __restrict__ partm, float* __restrict__ parts) {
    int w = threadIdx.x >> 6, lane = threadIdx.x & 63;
    int lrow = lane & 15, lhi = lane >> 4;
    int ubase = blockIdx.x * 128 + w * 32;
    int p = blockIdx.y;

    short8 a[2][4];
#pragma unroll
    for (int s2 = 0; s2 < 2; ++s2)
#pragma unroll
        for (int kc = 0; kc < 4; ++kc)
            a[s2][kc] = *(const short8*)(Ubf + (size_t)(ubase + s2 * 16 + lrow) * DD + kc * 32 + lhi * 8);

    float m[2][4], s[2][4];
#pragma unroll
    for (int s2 = 0; s2 < 2; ++s2)
#pragma unroll
        for (int r = 0; r < 4; ++r) { m[s2][r] = -1e30f; s[s2][r] = 0.f; }

    int c0 = p * TILES_PP * 16;
    for (int tile = 0; tile < TILES_PP; ++tile) {
        int comp = c0 + tile * 16 + lrow;
        f32x4 acc0 = {0.f, 0.f, 0.f, 0.f};
        f32x4 acc1 = {0.f, 0.f, 0.f, 0.f};
#pragma unroll
        for (int kc = 0; kc < 4; ++kc) {
            short8 b = *(const short8*)(Cbf + (size_t)comp * DD + kc * 32 + lhi * 8);
            acc0 = __builtin_amdgcn_mfma_f32_16x16x32_bf16(a[0][kc], b, acc0, 0, 0, 0);
            acc1 = __builtin_amdgcn_mfma_f32_16x16x32_bf16(a[1][kc], b, acc1, 0, 0, 0);
        }
#pragma unroll
        for (int r = 0; r < 4; ++r) {
            lse_push(acc0[r], m[0][r], s[0][r]);
            lse_push(acc1[r], m[1][r], s[1][r]);
        }
    }

#pragma unroll
    for (int s2 = 0; s2 < 2; ++s2)
#pragma unroll
        for (int r = 0; r < 4; ++r) {
            float M = m[s2][r], S = s[s2][r];
#pragma unroll
            for (int o = 1; o < 16; o <<= 1) {
                float M2 = __shfl_xor(M, o, 64);
                float S2 = __shfl_xor(S, o, 64);
                if (M2 > M) { S = S * __expf(M - M2) + S2; M = M2; }
                else { S += S2 * __expf(M2 - M); }
            }
            if (lrow == 0) {
                int u = ubase + s2 * 16 + lhi * 4 + r;
                partm[(size_t)u * PPART + p] = M;
                parts[(size_t)u * PPART + p] = S;
            }
        }
}

// ---------------- finish (wave-per-user) ----------------
// grid 256 blocks x 256 threads = 1024 waves; wave w of block b owns user b*4+w.
__global__ __launch_bounds__(256) void finish2_k(const float* __restrict__ hfin, const float* __restrict__ ent,
                                                 const float* __restrict__ rel, const int* __restrict__ ub,
                                                 const int* __restrict__ ct, const int* __restrict__ jt,
                                                 const float* __restrict__ partm, const float* __restrict__ parts,
                                                 float* __restrict__ out) {
    __shared__ float s_u[4][128];
    int w = threadIdx.x >> 6, lane = threadIdx.x & 63;
    int u = blockIdx.x * 4 + w;

    const float* up = hfin + (size_t)ub[u] * DD;
    float u0 = up[lane], u1 = up[lane + 64];
    s_u[w][lane] = u0;
    s_u[w][lane + 64] = u1;   // same-wave LDS write->read, no barrier needed

    // pos_c / pos_j lane-partials
    const float* tcp = ent + (size_t)(USER_NUM_ + ct[u]) * DD;
    float pc = u0 * tcp[lane] + u1 * tcp[lane + 64];
    const float* tjp = rel + (size_t)jt[u] * DD;
    float pj = u0 * tjp[lane] + u1 * tjp[lane + 64];
#pragma unroll
    for (int o = 1; o < 64; o <<= 1) {
        pc += __shfl_xor(pc, o, 64);
        pj += __shfl_xor(pj, o, 64);
    }

    // merge 125 comp-LSE partials: lane holds p=lane and p=lane+64
    float M = partm[(size_t)u * PPART + lane];
    float S = parts[(size_t)u * PPART + lane];
    if (lane + 64 < PPART)
        lse_merge(M, S, partm[(size_t)u * PPART + lane + 64], parts[(size_t)u * PPART + lane + 64]);
#pragma unroll
    for (int o = 1; o < 64; o <<= 1) {
        float M2 = __shfl_xor(M, o, 64);
        float S2 = __shfl_xor(S, o, 64);
        lse_merge(M, S, M2, S2);
    }
    float lse_c = M + logf(S);

    // job logits: lane owns job j1=lane (always <100) and j2=lane+64 (valid lanes 0..35)
    int j1 = lane, j2 = lane + 64;
    bool v2 = j2 < (REL_NUM_ / 2);
    const float* r1 = rel + (size_t)j1 * DD;
    const float* r2 = rel + (size_t)(v2 ? j2 : 0) * DD;
    float d1 = 0.f, d2 = 0.f;
#pragma unroll 16
    for (int k = 0; k < DD; ++k) {
        float uk = s_u[w][k];
        d1 = fmaf(uk, r1[k], d1);
        d2 = fmaf(uk, r2[k], d2);
    }
    float Mj = d1, Sj = 1.f;
    if (v2) lse_push(d2, Mj, Sj);
#pragma unroll
    for (int o = 1; o < 64; o <<= 1) {
        float M2 = __shfl_xor(Mj, o, 64);
        float S2 = __shfl_xor(Sj, o, 64);
        lse_merge(Mj, Sj, M2, S2);
    }
    float lse_j = Mj + logf(Sj);

    if (lane == 0) {
        atomicAdd(&out[0], lse_c - pc);
        atomicAdd(&out[1], lse_j - pj);
    }
}

// ---------------- host ----------------
static inline size_t rup(size_t x) { return (x + 255) & ~(size_t)255; }

extern "C" void kernel_launch(void* const* d_in, const int* in_sizes, int n_in,
                              void* d_out, int out_size, void* d_ws, size_t ws_size,
                              hipStream_t stream) {
    const float* ent_emb = (const float*)d_in[0];
    const float* c0_emb  = (const float*)d_in[1];
    const float* rel_emb = (const float*)d_in[2];
    const float* W_ih    = (const float*)d_in[3];
    const float* W_hh    = (const float*)d_in[4];
    const float* b_ih    = (const float*)d_in[5];
    const float* b_hh    = (const float*)d_in[6];
    const int* src       = (const int*)d_in[7];
    const int* dst       = (const int*)d_in[8];
    const int* rel_idx   = (const int*)d_in[9];
    const int* seed_idx  = (const int*)d_in[10];
    const int* ubatch    = (const int*)d_in[11];
    const int* ctarg     = (const int*)d_in[12];
    const int* jtarg     = (const int*)d_in[13];
    float* out = (float*)d_out;

    const size_t HB = (size_t)EN * DD * sizeof(float);   // 76,801,024

    char* base = (char*)d_ws;
    float* h0 = (float*)base;
    float* h1 = (float*)(base + HB);
    float* cbuf = (float*)(base + 2 * HB);

    auto place = [&](int NT, int** off, int** pairs, int** cnt, int** incl, int** cur,
                     int** bsums, short** Wt, float** bsumv) -> size_t {
        size_t o = 3 * HB;
        *off   = (int*)(base + o); o += rup((size_t)NT * ENP * 4);
        *pairs = (int*)(base + o); o += rup((size_t)NT * EE * 4);
        *cnt   = (int*)(base + o); o += rup((size_t)NT * EN * 4);
        *incl  = (int*)(base + o); o += rup((size_t)NT * EN * 4);
        *cur   = (int*)(base + o); o += rup((size_t)NT * EN * 4);
        *bsums = (int*)(base + o); o += rup((size_t)NT * NBLK * 4);
        *Wt    = (short*)(base + o); o += rup(512 * 256 * 2);
        *bsumv = (float*)(base + o); o += rup(512 * 4);
        return o;
    };

    int *off, *pairs, *cnt, *incl, *cur, *bsums;
    short* Wt; float* bsumv;
    size_t need12 = place(TT, &off, &pairs, &cnt, &incl, &cur, &bsums, &Wt, &bsumv);
    int NT = (ws_size >= need12) ? TT : 1;
    if (NT != TT) place(1, &off, &pairs, &cnt, &incl, &cur, &bsums, &Wt, &bsumv);

    // comp-phase buffers alias cbuf region (dead after step loop)
    char* q = (char*)cbuf;
    short* Cbf = (short*)q;            q += rup((size_t)COMP_NUM_ * DD * 2);  // 12.8 MB
    short* Ubf = (short*)q;            q += rup((size_t)BB * DD * 2);
    float* partm = (float*)q;          q += rup((size_t)BB * PPART * 4);
    float* parts = (float*)q;

    hipMemsetAsync(d_out, 0, 2 * sizeof(float), stream);

    const int n4 = EN * DD / 4;
    const int gcpy = (n4 + 255) / 256;
    const int ge = (EE + 255) / 256;

    prepW_k<<<512, 256, 0, stream>>>(W_ih, W_hh, b_ih, b_hh, Wt, bsumv);
    copy4_k<<<gcpy, 256, 0, stream>>>((float4*)h0, (const float4*)ent_emb, n4);
    copy4_k<<<gcpy, 256, 0, stream>>>((float4*)cbuf, (const float4*)c0_emb, n4);

    auto build = [&](int t0, int nt) {
        zero_i32_k<<<(nt * EN + 255) / 256, 256, 0, stream>>>(cnt, nt * EN);
        hist_k<<<dim3(ge, nt), 256, 0, stream>>>(cnt, dst, t0);
        scanA_k<<<dim3(NBLK, nt), 256, 0, stream>>>(cnt, incl, bsums);
        scanB_k<<<nt, 1024, 0, stream>>>(bsums);
        scanC_k<<<dim3(NBLK, nt), 256, 0, stream>>>(cnt, incl, bsums, off, cur);
        reorder_k<<<dim3(ge, nt), 256, 0, stream>>>(src, dst, rel_idx, cur, pairs, t0);
    };

    if (NT == TT) build(0, TT);

    float* hold = h0;
    float* hnew = h1;
    const int gagg = (EN + 1) / 2;

    for (int t = 0; t < TT; ++t) {
        if (NT == 1) build(t, 1);
        int slot = (NT == TT) ? t : 0;
        agg_k<<<gagg, 256, 0, stream>>>(hold, hnew, rel_emb, off, pairs, slot);
        lstm_k<<<SS / 32, 256, 0, stream>>>(hold, hnew, cbuf, Wt, bsumv, seed_idx + (size_t)t * SS);
        float* tmp = hold; hold = hnew; hnew = tmp;
    }

    // NOTE: cbuf region is reused for Cbf/Ubf/partials from here on
    packC_k<<<(COMP_NUM_ * DD / 4 + 255) / 256, 256, 0, stream>>>(ent_emb, Cbf);
    packU_k<<<(BB * DD + 255) / 256, 256, 0, stream>>>(hold, ubatch, Ubf);
    comp_mfma_k<<<dim3(BB / 128, PPART), 256, 0, stream>>>(Ubf, Cbf, partm, parts);
    finish2_k<<<BB / 4, 256, 0, stream>>>(hold, ent_emb, rel_emb, ubatch, ctarg, jtarg,
                                          partm, parts, out);
}

// Round 4
// 1321.632 us; speedup vs baseline: 2.2608x; 1.5791x over previous
//
#include <hip/hip_runtime.h>
#include <math.h>

typedef __attribute__((ext_vector_type(8))) short short8;
typedef __attribute__((ext_vector_type(4))) float f32x4;

#define USER_NUM_  100000
#define COMP_NUM_  50000
#define EN         150002
#define ENP        (EN + 1)
#define REL_NUM_   200
#define DD         128
#define TT         12
#define EE         250000
#define SS         20000
#define BB         1024
#define NBLK       587      // ceil(EN/256)
#define PPART      125      // comp partitions
#define TILES_PP   25       // 16-comp tiles per partition (125*25*16 = 50000)

__device__ inline unsigned short f2bf(float f) {
    unsigned u = __float_as_uint(f);
    unsigned r = (u + 0x7fffu + ((u >> 16) & 1u)) >> 16;
    return (unsigned short)r;
}

__device__ inline float bf2f(unsigned short u) {
    return __uint_as_float((unsigned)u << 16);
}

__device__ inline float sigmoidf_(float x) { return 1.f / (1.f + __expf(-x)); }

__device__ inline void lse_push(float v, float& m, float& s) {
    if (v <= m) { s += __expf(v - m); }
    else { s = s * __expf(m - v) + 1.f; m = v; }
}

__device__ inline void lse_merge(float& M, float& S, float M2, float S2) {
    float Mn = fmaxf(M, M2);
    S = S * __expf(M - Mn) + S2 * __expf(M2 - Mn);
    M = Mn;
}

// ---------------- utility ----------------
__global__ __launch_bounds__(256) void copy4_k(float4* __restrict__ dst, const float4* __restrict__ src, int n4) {
    int i = blockIdx.x * 256 + threadIdx.x;
    if (i < n4) dst[i] = src[i];
}

__global__ __launch_bounds__(256) void packH0_k(const float* __restrict__ ent, ushort4* __restrict__ h, int n4) {
    int i = blockIdx.x * 256 + threadIdx.x;
    if (i >= n4) return;
    float4 v = ((const float4*)ent)[i];
    ushort4 o;
    o.x = f2bf(v.x); o.y = f2bf(v.y); o.z = f2bf(v.z); o.w = f2bf(v.w);
    h[i] = o;
}

__global__ __launch_bounds__(256) void zero_i32_k(int* __restrict__ p, int n) {
    int i = blockIdx.x * 256 + threadIdx.x;
    if (i < n) p[i] = 0;
}

__global__ __launch_bounds__(256) void prepW_k(const float* __restrict__ Wih, const float* __restrict__ Whh,
                                               const float* __restrict__ bih, const float* __restrict__ bhh,
                                               short* __restrict__ Wt, float* __restrict__ bsum) {
    int n = blockIdx.x;      // 0..511
    int k = threadIdx.x;     // 0..255
    float v = (k < 128) ? Wih[n * 128 + k] : Whh[n * 128 + (k - 128)];
    Wt[n * 256 + k] = (short)f2bf(v);
    if (k == 0) bsum[n] = bih[n] + bhh[n];
}

// ---------------- CSR build (12 steps at once via blockIdx.y) ----------------
__global__ __launch_bounds__(256) void hist_k(int* __restrict__ cnt, const int* __restrict__ dst, int t0) {
    int slot = blockIdx.y;
    int e = blockIdx.x * 256 + threadIdx.x;
    if (e < EE) atomicAdd(&cnt[slot * EN + dst[(size_t)(t0 + slot) * EE + e]], 1);
}

__global__ __launch_bounds__(256) void scanA_k(const int* __restrict__ cnt, int* __restrict__ incl,
                                               int* __restrict__ bsums) {
    int slot = blockIdx.y;
    int tid = threadIdx.x;
    int i = blockIdx.x * 256 + tid;
    int v = (i < EN) ? cnt[slot * EN + i] : 0;
    __shared__ int lds[256];
    lds[tid] = v; __syncthreads();
#pragma unroll
    for (int o = 1; o < 256; o <<= 1) {
        int x = (tid >= o) ? lds[tid - o] : 0;
        __syncthreads();
        lds[tid] += x;
        __syncthreads();
    }
    int vin = lds[tid];
    if (i < EN) incl[slot * EN + i] = vin;
    if (tid == 255) bsums[slot * NBLK + blockIdx.x] = vin;
}

__global__ __launch_bounds__(1024) void scanB_k(int* __restrict__ bsums) {
    int slot = blockIdx.x;
    int tid = threadIdx.x;
    int v = (tid < NBLK) ? bsums[slot * NBLK + tid] : 0;
    __shared__ int lds[1024];
    lds[tid] = v; __syncthreads();
#pragma unroll
    for (int o = 1; o < 1024; o <<= 1) {
        int x = (tid >= o) ? lds[tid - o] : 0;
        __syncthreads();
        lds[tid] += x;
        __syncthreads();
    }
    if (tid < NBLK) bsums[slot * NBLK + tid] = lds[tid] - v;  // exclusive
}

__global__ __launch_bounds__(256) void scanC_k(const int* __restrict__ cnt, const int* __restrict__ incl,
                                               const int* __restrict__ bsums, int* __restrict__ off,
                                               int* __restrict__ cur) {
    int slot = blockIdx.y;
    int i = blockIdx.x * 256 + threadIdx.x;
    if (i >= EN) return;
    int c = cnt[slot * EN + i];
    int ex = incl[slot * EN + i] - c + bsums[slot * NBLK + blockIdx.x];
    off[slot * ENP + i] = ex;
    cur[slot * EN + i] = ex;
    if (i == EN - 1) off[slot * ENP + EN] = ex + c;
}

__global__ __launch_bounds__(256) void reorder_k(const int* __restrict__ src, const int* __restrict__ dst,
                                                 const int* __restrict__ rel, int* __restrict__ cur,
                                                 int* __restrict__ pairs, int t0) {
    int slot = blockIdx.y;
    int e = blockIdx.x * 256 + threadIdx.x;
    if (e >= EE) return;
    size_t gi = (size_t)(t0 + slot) * EE + e;
    int d = dst[gi];
    int pos = atomicAdd(&cur[slot * EN + d], 1);
    pairs[(size_t)slot * EE + pos] = src[gi] | (rel[gi] << 18);
}

// ---------------- fused aggregate: x[d] = h[d] + (1/cnt)*sum h[src]*rel[r] (bf16 h) -----
// 32 lanes per entity (4 bf16 each), 8 entities per 256-block.
__global__ __launch_bounds__(256) void agg_k(const unsigned short* __restrict__ hold,
                                             unsigned short* __restrict__ hnew,
                                             const float* __restrict__ relemb, const int* __restrict__ off,
                                             const int* __restrict__ pairs, int slot) {
    int tid = threadIdx.x;
    int d = blockIdx.x * 8 + (tid >> 5);
    int l = tid & 31;
    if (d >= EN) return;
    const int* offp = off + (size_t)slot * ENP;
    int e0 = offp[d], e1 = offp[d + 1];
    const int* pp = pairs + (size_t)slot * EE;
    float a0 = 0.f, a1 = 0.f, a2 = 0.f, a3 = 0.f;
    for (int e = e0; e < e1; ++e) {
        int pk = pp[e];
        int s = pk & 0x3FFFF;
        int r = pk >> 18;
        ushort4 hv = *(const ushort4*)(hold + (size_t)s * DD + l * 4);
        float4 rv = *(const float4*)(relemb + (size_t)r * DD + l * 4);
        a0 = fmaf(bf2f(hv.x), rv.x, a0);
        a1 = fmaf(bf2f(hv.y), rv.y, a1);
        a2 = fmaf(bf2f(hv.z), rv.z, a2);
        a3 = fmaf(bf2f(hv.w), rv.w, a3);
    }
    ushort4 hd = *(const ushort4*)(hold + (size_t)d * DD + l * 4);
    int c = e1 - e0;
    float inv = (c > 0) ? 1.f / (float)c : 0.f;
    ushort4 o;
    o.x = f2bf(fmaf(a0, inv, bf2f(hd.x)));
    o.y = f2bf(fmaf(a1, inv, bf2f(hd.y)));
    o.z = f2bf(fmaf(a2, inv, bf2f(hd.z)));
    o.w = f2bf(fmaf(a3, inv, bf2f(hd.w)));
    *(ushort4*)(hnew + (size_t)d * DD + l * 4) = o;
}

// ---------------- LSTM on seed rows (MFMA bf16, bf16 h state) ----------------
__global__ __launch_bounds__(256) void lstm_k(const unsigned short* __restrict__ hold,
                                              unsigned short* __restrict__ hnew,
                                              float* __restrict__ cbuf, const short* __restrict__ Wt,
                                              const float* __restrict__ bsum, const int* __restrict__ seed) {
    int w = threadIdx.x >> 6;
    int lane = threadIdx.x & 63;
    int lrow = lane & 15, lhi = lane >> 4;
    int m0 = blockIdx.x * 32;
    int w32 = w * 32;

    const unsigned short* pxi[2];
    const unsigned short* php[2];
#pragma unroll
    for (int mi = 0; mi < 2; ++mi) {
        int m = m0 + mi * 16 + lrow;
        int sd = seed[m];
        pxi[mi] = hnew + (size_t)sd * DD;
        php[mi] = hold + (size_t)sd * DD;
    }

    f32x4 acc[2][4][2];
#pragma unroll
    for (int mi = 0; mi < 2; ++mi)
#pragma unroll
        for (int g = 0; g < 4; ++g)
#pragma unroll
            for (int s = 0; s < 2; ++s)
                acc[mi][g][s] = (f32x4){0.f, 0.f, 0.f, 0.f};

#pragma unroll
    for (int kk = 0; kk < 8; ++kk) {
        int klane = kk * 32 + lhi * 8;
        short8 af[2];
#pragma unroll
        for (int mi = 0; mi < 2; ++mi) {
            const unsigned short* p = (klane < 128) ? (pxi[mi] + klane) : (php[mi] + (klane - 128));
            af[mi] = *(const short8*)p;
        }
#pragma unroll
        for (int g = 0; g < 4; ++g)
#pragma unroll
            for (int s = 0; s < 2; ++s) {
                int col = g * 128 + w32 + s * 16 + lrow;
                short8 bf = *(const short8*)(Wt + col * 256 + klane);
                acc[0][g][s] = __builtin_amdgcn_mfma_f32_16x16x32_bf16(af[0], bf, acc[0][g][s], 0, 0, 0);
                acc[1][g][s] = __builtin_amdgcn_mfma_f32_16x16x32_bf16(af[1], bf, acc[1][g][s], 0, 0, 0);
            }
    }

    __syncthreads();  // all xi reads done before seed rows are overwritten

#pragma unroll
    for (int mi = 0; mi < 2; ++mi) {
#pragma unroll
        for (int r = 0; r < 4; ++r) {
            int m = m0 + mi * 16 + lhi * 4 + r;
            int sd = seed[m];
#pragma unroll
            for (int s = 0; s < 2; ++s) {
                int d = w32 + s * 16 + lrow;
                float ig = acc[mi][0][s][r] + bsum[d];
                float fg = acc[mi][1][s][r] + bsum[128 + d];
                float gg = acc[mi][2][s][r] + bsum[256 + d];
                float og = acc[mi][3][s][r] + bsum[384 + d];
                float cp = cbuf[(size_t)sd * DD + d];
                float cn = sigmoidf_(fg) * cp + sigmoidf_(ig) * tanhf(gg);
                float hn = sigmoidf_(og) * tanhf(cn);
                cbuf[(size_t)sd * DD + d] = cn;
                hnew[(size_t)sd * DD + d] = f2bf(hn);
            }
        }
    }
}

// ---------------- comp loss: bf16 packers ----------------
__global__ __launch_bounds__(256) void packC_k(const float* __restrict__ ent, short* __restrict__ Cbf) {
    int i4 = blockIdx.x * 256 + threadIdx.x;   // over 50000*128/4 = 1,600,000
    if (i4 >= COMP_NUM_ * DD / 4) return;
    float4 v = ((const float4*)(ent + (size_t)USER_NUM_ * DD))[i4];
    short* o = Cbf + (size_t)i4 * 4;
    o[0] = (short)f2bf(v.x); o[1] = (short)f2bf(v.y); o[2] = (short)f2bf(v.z); o[3] = (short)f2bf(v.w);
}

__global__ __launch_bounds__(256) void packU_k(const unsigned short* __restrict__ hfin, const int* __restrict__ ub,
                                               short* __restrict__ Ubf) {
    int i = blockIdx.x * 256 + threadIdx.x;    // over 1024*128
    if (i >= BB * DD) return;
    int u = i >> 7, k = i & 127;
    Ubf[i] = (short)hfin[(size_t)ub[u] * DD + k];
}

// ---------------- comp loss: MFMA GEMM + per-lane online LSE ----------------
__global__ __launch_bounds__(256) void comp_mfma_k(const short* __restrict__ Ubf, const short* __restrict__ Cbf,
                                                   float* __restrict__ partm, float* __restrict__ parts) {
    int w = threadIdx.x >> 6, lane = threadIdx.x & 63;
    int lrow = lane & 15, lhi = lane >> 4;
    int ubase = blockIdx.x * 128 + w * 32;
    int p = blockIdx.y;

    short8 a[2][4];
#pragma unroll
    for (int s2 = 0; s2 < 2; ++s2)
#pragma unroll
        for (int kc = 0; kc < 4; ++kc)
            a[s2][kc] = *(const short8*)(Ubf + (size_t)(ubase + s2 * 16 + lrow) * DD + kc * 32 + lhi * 8);

    float m[2][4], s[2][4];
#pragma unroll
    for (int s2 = 0; s2 < 2; ++s2)
#pragma unroll
        for (int r = 0; r < 4; ++r) { m[s2][r] = -1e30f; s[s2][r] = 0.f; }

    int c0 = p * TILES_PP * 16;
    for (int tile = 0; tile < TILES_PP; ++tile) {
        int comp = c0 + tile * 16 + lrow;
        f32x4 acc0 = {0.f, 0.f, 0.f, 0.f};
        f32x4 acc1 = {0.f, 0.f, 0.f, 0.f};
#pragma unroll
        for (int kc = 0; kc < 4; ++kc) {
            short8 b = *(const short8*)(Cbf + (size_t)comp * DD + kc * 32 + lhi * 8);
            acc0 = __builtin_amdgcn_mfma_f32_16x16x32_bf16(a[0][kc], b, acc0, 0, 0, 0);
            acc1 = __builtin_amdgcn_mfma_f32_16x16x32_bf16(a[1][kc], b, acc1, 0, 0, 0);
        }
#pragma unroll
        for (int r = 0; r < 4; ++r) {
            lse_push(acc0[r], m[0][r], s[0][r]);
            lse_push(acc1[r], m[1][r], s[1][r]);
        }
    }

#pragma unroll
    for (int s2 = 0; s2 < 2; ++s2)
#pragma unroll
        for (int r = 0; r < 4; ++r) {
            float M = m[s2][r], S = s[s2][r];
#pragma unroll
            for (int o = 1; o < 16; o <<= 1) {
                float M2 = __shfl_xor(M, o, 64);
                float S2 = __shfl_xor(S, o, 64);
                if (M2 > M) { S = S * __expf(M - M2) + S2; M = M2; }
                else { S += S2 * __expf(M2 - M); }
            }
            if (lrow == 0) {
                int u = ubase + s2 * 16 + lhi * 4 + r;
                partm[(size_t)u * PPART + p] = M;
                parts[(size_t)u * PPART + p] = S;
            }
        }
}

// ---------------- finish (wave-per-user) ----------------
__global__ __launch_bounds__(256) void finish2_k(const unsigned short* __restrict__ hfin,
                                                 const float* __restrict__ ent,
                                                 const float* __restrict__ rel, const int* __restrict__ ub,
                                                 const int* __restrict__ ct, const int* __restrict__ jt,
                                                 const float* __restrict__ partm, const float* __restrict__ parts,
                                                 float* __restrict__ out) {
    __shared__ float s_u[4][128];
    int w = threadIdx.x >> 6, lane = threadIdx.x & 63;
    int u = blockIdx.x * 4 + w;

    const unsigned short* up = hfin + (size_t)ub[u] * DD;
    float u0 = bf2f(up[lane]), u1 = bf2f(up[lane + 64]);
    s_u[w][lane] = u0;
    s_u[w][lane + 64] = u1;   // same-wave LDS write->read, no barrier needed

    // pos_c / pos_j lane-partials
    const float* tcp = ent + (size_t)(USER_NUM_ + ct[u]) * DD;
    float pc = u0 * tcp[lane] + u1 * tcp[lane + 64];
    const float* tjp = rel + (size_t)jt[u] * DD;
    float pj = u0 * tjp[lane] + u1 * tjp[lane + 64];
#pragma unroll
    for (int o = 1; o < 64; o <<= 1) {
        pc += __shfl_xor(pc, o, 64);
        pj += __shfl_xor(pj, o, 64);
    }

    // merge 125 comp-LSE partials: lane holds p=lane and p=lane+64
    float M = partm[(size_t)u * PPART + lane];
    float S = parts[(size_t)u * PPART + lane];
    if (lane + 64 < PPART)
        lse_merge(M, S, partm[(size_t)u * PPART + lane + 64], parts[(size_t)u * PPART + lane + 64]);
#pragma unroll
    for (int o = 1; o < 64; o <<= 1) {
        float M2 = __shfl_xor(M, o, 64);
        float S2 = __shfl_xor(S, o, 64);
        lse_merge(M, S, M2, S2);
    }
    float lse_c = M + logf(S);

    // job logits: lane owns job j1=lane (<100) and j2=lane+64 (valid lanes 0..35)
    int j1 = lane, j2 = lane + 64;
    bool v2 = j2 < (REL_NUM_ / 2);
    const float* r1 = rel + (size_t)j1 * DD;
    const float* r2 = rel + (size_t)(v2 ? j2 : 0) * DD;
    float d1 = 0.f, d2 = 0.f;
#pragma unroll 16
    for (int k = 0; k < DD; ++k) {
        float uk = s_u[w][k];
        d1 = fmaf(uk, r1[k], d1);
        d2 = fmaf(uk, r2[k], d2);
    }
    float Mj = d1, Sj = 1.f;
    if (v2) lse_push(d2, Mj, Sj);
#pragma unroll
    for (int o = 1; o < 64; o <<= 1) {
        float M2 = __shfl_xor(Mj, o, 64);
        float S2 = __shfl_xor(Sj, o, 64);
        lse_merge(Mj, Sj, M2, S2);
    }
    float lse_j = Mj + logf(Sj);

    if (lane == 0) {
        atomicAdd(&out[0], lse_c - pc);
        atomicAdd(&out[1], lse_j - pj);
    }
}

// ---------------- host ----------------
static inline size_t rup(size_t x) { return (x + 255) & ~(size_t)255; }

extern "C" void kernel_launch(void* const* d_in, const int* in_sizes, int n_in,
                              void* d_out, int out_size, void* d_ws, size_t ws_size,
                              hipStream_t stream) {
    const float* ent_emb = (const float*)d_in[0];
    const float* c0_emb  = (const float*)d_in[1];
    const float* rel_emb = (const float*)d_in[2];
    const float* W_ih    = (const float*)d_in[3];
    const float* W_hh    = (const float*)d_in[4];
    const float* b_ih    = (const float*)d_in[5];
    const float* b_hh    = (const float*)d_in[6];
    const int* src       = (const int*)d_in[7];
    const int* dst       = (const int*)d_in[8];
    const int* rel_idx   = (const int*)d_in[9];
    const int* seed_idx  = (const int*)d_in[10];
    const int* ubatch    = (const int*)d_in[11];
    const int* ctarg     = (const int*)d_in[12];
    const int* jtarg     = (const int*)d_in[13];
    float* out = (float*)d_out;

    const size_t HBH = (size_t)EN * DD * 2;              // bf16 h buffer: 38,400,512
    const size_t HBF = (size_t)EN * DD * sizeof(float);  // f32 c buffer: 76,801,024

    char* base = (char*)d_ws;
    unsigned short* h0 = (unsigned short*)base;
    unsigned short* h1 = (unsigned short*)(base + HBH);
    float* cbuf = (float*)(base + 2 * HBH);

    auto place = [&](int NT, int** off, int** pairs, int** cnt, int** incl, int** cur,
                     int** bsums, short** Wt, float** bsumv) -> size_t {
        size_t o = 2 * HBH + HBF;
        *off   = (int*)(base + o); o += rup((size_t)NT * ENP * 4);
        *pairs = (int*)(base + o); o += rup((size_t)NT * EE * 4);
        *cnt   = (int*)(base + o); o += rup((size_t)NT * EN * 4);
        *incl  = (int*)(base + o); o += rup((size_t)NT * EN * 4);
        *cur   = (int*)(base + o); o += rup((size_t)NT * EN * 4);
        *bsums = (int*)(base + o); o += rup((size_t)NT * NBLK * 4);
        *Wt    = (short*)(base + o); o += rup(512 * 256 * 2);
        *bsumv = (float*)(base + o); o += rup(512 * 4);
        return o;
    };

    int *off, *pairs, *cnt, *incl, *cur, *bsums;
    short* Wt; float* bsumv;
    size_t need12 = place(TT, &off, &pairs, &cnt, &incl, &cur, &bsums, &Wt, &bsumv);
    int NT = (ws_size >= need12) ? TT : 1;
    if (NT != TT) place(1, &off, &pairs, &cnt, &incl, &cur, &bsums, &Wt, &bsumv);

    // comp-phase buffers alias cbuf region (dead after step loop)
    char* q = (char*)cbuf;
    short* Cbf = (short*)q;            q += rup((size_t)COMP_NUM_ * DD * 2);  // 12.8 MB
    short* Ubf = (short*)q;            q += rup((size_t)BB * DD * 2);
    float* partm = (float*)q;          q += rup((size_t)BB * PPART * 4);
    float* parts = (float*)q;

    hipMemsetAsync(d_out, 0, 2 * sizeof(float), stream);

    const int n4 = EN * DD / 4;
    const int gcpy = (n4 + 255) / 256;
    const int ge = (EE + 255) / 256;

    prepW_k<<<512, 256, 0, stream>>>(W_ih, W_hh, b_ih, b_hh, Wt, bsumv);
    packH0_k<<<gcpy, 256, 0, stream>>>(ent_emb, (ushort4*)h0, n4);
    copy4_k<<<gcpy, 256, 0, stream>>>((float4*)cbuf, (const float4*)c0_emb, n4);

    auto build = [&](int t0, int nt) {
        zero_i32_k<<<(nt * EN + 255) / 256, 256, 0, stream>>>(cnt, nt * EN);
        hist_k<<<dim3(ge, nt), 256, 0, stream>>>(cnt, dst, t0);
        scanA_k<<<dim3(NBLK, nt), 256, 0, stream>>>(cnt, incl, bsums);
        scanB_k<<<nt, 1024, 0, stream>>>(bsums);
        scanC_k<<<dim3(NBLK, nt), 256, 0, stream>>>(cnt, incl, bsums, off, cur);
        reorder_k<<<dim3(ge, nt), 256, 0, stream>>>(src, dst, rel_idx, cur, pairs, t0);
    };

    if (NT == TT) build(0, TT);

    unsigned short* hold = h0;
    unsigned short* hnew = h1;
    const int gagg = (EN + 7) / 8;

    for (int t = 0; t < TT; ++t) {
        if (NT == 1) build(t, 1);
        int slot = (NT == TT) ? t : 0;
        agg_k<<<gagg, 256, 0, stream>>>(hold, hnew, rel_emb, off, pairs, slot);
        lstm_k<<<SS / 32, 256, 0, stream>>>(hold, hnew, cbuf, Wt, bsumv, seed_idx + (size_t)t * SS);
        unsigned short* tmp = hold; hold = hnew; hnew = tmp;
    }

    // NOTE: cbuf region is reused for Cbf/Ubf/partials from here on
    packC_k<<<(COMP_NUM_ * DD / 4 + 255) / 256, 256, 0, stream>>>(ent_emb, Cbf);
    packU_k<<<(BB * DD + 255) / 256, 256, 0, stream>>>(hold, ubatch, Ubf);
    comp_mfma_k<<<dim3(BB / 128, PPART), 256, 0, stream>>>(Ubf, Cbf, partm, parts);
    finish2_k<<<BB / 4, 256, 0, stream>>>(hold, ent_emb, rel_emb, ubatch, ctarg, jtarg,
                                          partm, parts, out);
}

// Round 5
// 1153.627 us; speedup vs baseline: 2.5900x; 1.1456x over previous
//
#include <hip/hip_runtime.h>
#include <math.h>

typedef __attribute__((ext_vector_type(8))) short short8;
typedef __attribute__((ext_vector_type(8))) unsigned short u16x8;
typedef __attribute__((ext_vector_type(4))) float f32x4;

#define USER_NUM_  100000
#define COMP_NUM_  50000
#define EN         150002
#define ENP        (EN + 1)
#define REL_NUM_   200
#define DD         128
#define TT         12
#define EE         250000
#define SS         20000
#define BB         1024
#define NBLK       587      // ceil(EN/256)
#define PPART      125      // comp partitions
#define TILES_PP   25       // 16-comp tiles per partition (125*25*16 = 50000)

__device__ inline unsigned short f2bf(float f) {
    unsigned u = __float_as_uint(f);
    unsigned r = (u + 0x7fffu + ((u >> 16) & 1u)) >> 16;
    return (unsigned short)r;
}

__device__ inline float bf2f(unsigned short u) {
    return __uint_as_float((unsigned)u << 16);
}

__device__ inline float sigmoidf_(float x) { return 1.f / (1.f + __expf(-x)); }

__device__ inline void lse_push(float v, float& m, float& s) {
    if (v <= m) { s += __expf(v - m); }
    else { s = s * __expf(m - v) + 1.f; m = v; }
}

__device__ inline void lse_merge(float& M, float& S, float M2, float S2) {
    float Mn = fmaxf(M, M2);
    S = S * __expf(M - Mn) + S2 * __expf(M2 - Mn);
    M = Mn;
}

// ---------------- utility ----------------
__global__ __launch_bounds__(256) void packBF_k(const float* __restrict__ src, ushort4* __restrict__ dst, int n4) {
    int i = blockIdx.x * 256 + threadIdx.x;
    if (i >= n4) return;
    float4 v = ((const float4*)src)[i];
    ushort4 o;
    o.x = f2bf(v.x); o.y = f2bf(v.y); o.z = f2bf(v.z); o.w = f2bf(v.w);
    dst[i] = o;
}

__global__ __launch_bounds__(256) void zero_i32_k(int* __restrict__ p, int n) {
    int i = blockIdx.x * 256 + threadIdx.x;
    if (i < n) p[i] = 0;
}

__global__ __launch_bounds__(256) void prepW_k(const float* __restrict__ Wih, const float* __restrict__ Whh,
                                               const float* __restrict__ bih, const float* __restrict__ bhh,
                                               short* __restrict__ Wt, float* __restrict__ bsum) {
    int n = blockIdx.x;      // 0..511
    int k = threadIdx.x;     // 0..255
    float v = (k < 128) ? Wih[n * 128 + k] : Whh[n * 128 + (k - 128)];
    Wt[n * 256 + k] = (short)f2bf(v);
    if (k == 0) bsum[n] = bih[n] + bhh[n];
}

// ---------------- CSR build: slot = blockIdx.x & 15 (slot->XCD affinity) ----------------
__global__ __launch_bounds__(256) void hist_k(int* __restrict__ cnt, const int* __restrict__ dst,
                                              int t0, int nt) {
    int slot = blockIdx.x & 15;
    if (slot >= nt) return;
    int e = (blockIdx.x >> 4) * 256 + threadIdx.x;
    if (e < EE) atomicAdd(&cnt[slot * EN + dst[(size_t)(t0 + slot) * EE + e]], 1);
}

__global__ __launch_bounds__(256) void scanA_k(const int* __restrict__ cnt, int* __restrict__ incl,
                                               int* __restrict__ bsums) {
    int slot = blockIdx.y;
    int tid = threadIdx.x;
    int i = blockIdx.x * 256 + tid;
    int v = (i < EN) ? cnt[slot * EN + i] : 0;
    __shared__ int lds[256];
    lds[tid] = v; __syncthreads();
#pragma unroll
    for (int o = 1; o < 256; o <<= 1) {
        int x = (tid >= o) ? lds[tid - o] : 0;
        __syncthreads();
        lds[tid] += x;
        __syncthreads();
    }
    int vin = lds[tid];
    if (i < EN) incl[slot * EN + i] = vin;
    if (tid == 255) bsums[slot * NBLK + blockIdx.x] = vin;
}

__global__ __launch_bounds__(1024) void scanB_k(int* __restrict__ bsums) {
    int slot = blockIdx.x;
    int tid = threadIdx.x;
    int v = (tid < NBLK) ? bsums[slot * NBLK + tid] : 0;
    __shared__ int lds[1024];
    lds[tid] = v; __syncthreads();
#pragma unroll
    for (int o = 1; o < 1024; o <<= 1) {
        int x = (tid >= o) ? lds[tid - o] : 0;
        __syncthreads();
        lds[tid] += x;
        __syncthreads();
    }
    if (tid < NBLK) bsums[slot * NBLK + tid] = lds[tid] - v;  // exclusive
}

__global__ __launch_bounds__(256) void scanC_k(const int* __restrict__ cnt, const int* __restrict__ incl,
                                               const int* __restrict__ bsums, int* __restrict__ off,
                                               int* __restrict__ cur) {
    int slot = blockIdx.y;
    int i = blockIdx.x * 256 + threadIdx.x;
    if (i >= EN) return;
    int c = cnt[slot * EN + i];
    int ex = incl[slot * EN + i] - c + bsums[slot * NBLK + blockIdx.x];
    off[slot * ENP + i] = ex;
    cur[slot * EN + i] = ex;
    if (i == EN - 1) off[slot * ENP + EN] = ex + c;
}

__global__ __launch_bounds__(256) void reorder_k(const int* __restrict__ src, const int* __restrict__ dst,
                                                 const int* __restrict__ rel, int* __restrict__ cur,
                                                 int* __restrict__ pairs, int t0, int nt) {
    int slot = blockIdx.x & 15;
    if (slot >= nt) return;
    int e = (blockIdx.x >> 4) * 256 + threadIdx.x;
    if (e >= EE) return;
    size_t gi = (size_t)(t0 + slot) * EE + e;
    int d = dst[gi];
    int pos = atomicAdd(&cur[slot * EN + d], 1);
    pairs[(size_t)slot * EE + pos] = src[gi] | (rel[gi] << 18);
}

// ---------------- fused aggregate: x[d] = h[d] + (1/cnt)*sum h[src]*rel[r] (bf16) -------
// 16 lanes per entity (8 bf16 = 16B each), 16 entities per 256-block.
__global__ __launch_bounds__(256) void agg_k(const unsigned short* __restrict__ hold,
                                             unsigned short* __restrict__ hnew,
                                             const unsigned short* __restrict__ Rbf,
                                             const int* __restrict__ off,
                                             const int* __restrict__ pairs, int slot) {
    int tid = threadIdx.x;
    int d = blockIdx.x * 16 + (tid >> 4);
    int l = tid & 15;
    if (d >= EN) return;
    const int* offp = off + (size_t)slot * ENP;
    int e0 = offp[d], e1 = offp[d + 1];
    const int* pp = pairs + (size_t)slot * EE;
    float acc[8];
#pragma unroll
    for (int j = 0; j < 8; ++j) acc[j] = 0.f;
    int e = e0;
    for (; e + 2 <= e1; e += 2) {
        int pk0 = pp[e], pk1 = pp[e + 1];
        u16x8 h0 = *(const u16x8*)(hold + (size_t)(pk0 & 0x3FFFF) * DD + l * 8);
        u16x8 r0 = *(const u16x8*)(Rbf + (size_t)(pk0 >> 18) * DD + l * 8);
        u16x8 h1 = *(const u16x8*)(hold + (size_t)(pk1 & 0x3FFFF) * DD + l * 8);
        u16x8 r1 = *(const u16x8*)(Rbf + (size_t)(pk1 >> 18) * DD + l * 8);
#pragma unroll
        for (int j = 0; j < 8; ++j)
            acc[j] = fmaf(bf2f(h1[j]), bf2f(r1[j]), fmaf(bf2f(h0[j]), bf2f(r0[j]), acc[j]));
    }
    if (e < e1) {
        int pk0 = pp[e];
        u16x8 h0 = *(const u16x8*)(hold + (size_t)(pk0 & 0x3FFFF) * DD + l * 8);
        u16x8 r0 = *(const u16x8*)(Rbf + (size_t)(pk0 >> 18) * DD + l * 8);
#pragma unroll
        for (int j = 0; j < 8; ++j)
            acc[j] = fmaf(bf2f(h0[j]), bf2f(r0[j]), acc[j]);
    }
    u16x8 hd = *(const u16x8*)(hold + (size_t)d * DD + l * 8);
    int c = e1 - e0;
    float inv = (c > 0) ? 1.f / (float)c : 0.f;
    u16x8 o;
#pragma unroll
    for (int j = 0; j < 8; ++j) o[j] = f2bf(fmaf(acc[j], inv, bf2f(hd[j])));
    *(u16x8*)(hnew + (size_t)d * DD + l * 8) = o;
}

// ---------------- LSTM on seed rows (MFMA bf16; bf16 h and c state) ----------------
__global__ __launch_bounds__(256) void lstm_k(const unsigned short* __restrict__ hold,
                                              unsigned short* __restrict__ hnew,
                                              unsigned short* __restrict__ cbuf, const short* __restrict__ Wt,
                                              const float* __restrict__ bsum, const int* __restrict__ seed) {
    int w = threadIdx.x >> 6;
    int lane = threadIdx.x & 63;
    int lrow = lane & 15, lhi = lane >> 4;
    int m0 = blockIdx.x * 32;
    int w32 = w * 32;

    const unsigned short* pxi[2];
    const unsigned short* php[2];
#pragma unroll
    for (int mi = 0; mi < 2; ++mi) {
        int m = m0 + mi * 16 + lrow;
        int sd = seed[m];
        pxi[mi] = hnew + (size_t)sd * DD;
        php[mi] = hold + (size_t)sd * DD;
    }

    f32x4 acc[2][4][2];
#pragma unroll
    for (int mi = 0; mi < 2; ++mi)
#pragma unroll
        for (int g = 0; g < 4; ++g)
#pragma unroll
            for (int s = 0; s < 2; ++s)
                acc[mi][g][s] = (f32x4){0.f, 0.f, 0.f, 0.f};

#pragma unroll
    for (int kk = 0; kk < 8; ++kk) {
        int klane = kk * 32 + lhi * 8;
        short8 af[2];
#pragma unroll
        for (int mi = 0; mi < 2; ++mi) {
            const unsigned short* p = (klane < 128) ? (pxi[mi] + klane) : (php[mi] + (klane - 128));
            af[mi] = *(const short8*)p;
        }
#pragma unroll
        for (int g = 0; g < 4; ++g)
#pragma unroll
            for (int s = 0; s < 2; ++s) {
                int col = g * 128 + w32 + s * 16 + lrow;
                short8 bf = *(const short8*)(Wt + col * 256 + klane);
                acc[0][g][s] = __builtin_amdgcn_mfma_f32_16x16x32_bf16(af[0], bf, acc[0][g][s], 0, 0, 0);
                acc[1][g][s] = __builtin_amdgcn_mfma_f32_16x16x32_bf16(af[1], bf, acc[1][g][s], 0, 0, 0);
            }
    }

    __syncthreads();  // all xi reads done before seed rows are overwritten

#pragma unroll
    for (int mi = 0; mi < 2; ++mi) {
#pragma unroll
        for (int r = 0; r < 4; ++r) {
            int m = m0 + mi * 16 + lhi * 4 + r;
            int sd = seed[m];
#pragma unroll
            for (int s = 0; s < 2; ++s) {
                int d = w32 + s * 16 + lrow;
                float ig = acc[mi][0][s][r] + bsum[d];
                float fg = acc[mi][1][s][r] + bsum[128 + d];
                float gg = acc[mi][2][s][r] + bsum[256 + d];
                float og = acc[mi][3][s][r] + bsum[384 + d];
                float cp = bf2f(cbuf[(size_t)sd * DD + d]);
                float cn = sigmoidf_(fg) * cp + sigmoidf_(ig) * tanhf(gg);
                float hn = sigmoidf_(og) * tanhf(cn);
                cbuf[(size_t)sd * DD + d] = f2bf(cn);
                hnew[(size_t)sd * DD + d] = f2bf(hn);
            }
        }
    }
}

// ---------------- comp loss: bf16 packers ----------------
__global__ __launch_bounds__(256) void packU_k(const unsigned short* __restrict__ hfin, const int* __restrict__ ub,
                                               short* __restrict__ Ubf) {
    int i = blockIdx.x * 256 + threadIdx.x;    // over 1024*128
    if (i >= BB * DD) return;
    int u = i >> 7, k = i & 127;
    Ubf[i] = (short)hfin[(size_t)ub[u] * DD + k];
}

// ---------------- comp loss: MFMA GEMM + per-lane online LSE ----------------
__global__ __launch_bounds__(256) void comp_mfma_k(const short* __restrict__ Ubf, const short* __restrict__ Cbf,
                                                   float* __restrict__ partm, float* __restrict__ parts) {
    int w = threadIdx.x >> 6, lane = threadIdx.x & 63;
    int lrow = lane & 15, lhi = lane >> 4;
    int ubase = blockIdx.x * 128 + w * 32;
    int p = blockIdx.y;

    short8 a[2][4];
#pragma unroll
    for (int s2 = 0; s2 < 2; ++s2)
#pragma unroll
        for (int kc = 0; kc < 4; ++kc)
            a[s2][kc] = *(const short8*)(Ubf + (size_t)(ubase + s2 * 16 + lrow) * DD + kc * 32 + lhi * 8);

    float m[2][4], s[2][4];
#pragma unroll
    for (int s2 = 0; s2 < 2; ++s2)
#pragma unroll
        for (int r = 0; r < 4; ++r) { m[s2][r] = -1e30f; s[s2][r] = 0.f; }

    int c0 = p * TILES_PP * 16;
    for (int tile = 0; tile < TILES_PP; ++tile) {
        int comp = c0 + tile * 16 + lrow;
        f32x4 acc0 = {0.f, 0.f, 0.f, 0.f};
        f32x4 acc1 = {0.f, 0.f, 0.f, 0.f};
#pragma unroll
        for (int kc = 0; kc < 4; ++kc) {
            short8 b = *(const short8*)(Cbf + (size_t)comp * DD + kc * 32 + lhi * 8);
            acc0 = __builtin_amdgcn_mfma_f32_16x16x32_bf16(a[0][kc], b, acc0, 0, 0, 0);
            acc1 = __builtin_amdgcn_mfma_f32_16x16x32_bf16(a[1][kc], b, acc1, 0, 0, 0);
        }
#pragma unroll
        for (int r = 0; r < 4; ++r) {
            lse_push(acc0[r], m[0][r], s[0][r]);
            lse_push(acc1[r], m[1][r], s[1][r]);
        }
    }

#pragma unroll
    for (int s2 = 0; s2 < 2; ++s2)
#pragma unroll
        for (int r = 0; r < 4; ++r) {
            float M = m[s2][r], S = s[s2][r];
#pragma unroll
            for (int o = 1; o < 16; o <<= 1) {
                float M2 = __shfl_xor(M, o, 64);
                float S2 = __shfl_xor(S, o, 64);
                if (M2 > M) { S = S * __expf(M - M2) + S2; M = M2; }
                else { S += S2 * __expf(M2 - M); }
            }
            if (lrow == 0) {
                int u = ubase + s2 * 16 + lhi * 4 + r;
                partm[(size_t)u * PPART + p] = M;
                parts[(size_t)u * PPART + p] = S;
            }
        }
}

// ---------------- finish (wave-per-user) ----------------
__global__ __launch_bounds__(256) void finish2_k(const unsigned short* __restrict__ hfin,
                                                 const float* __restrict__ ent,
                                                 const float* __restrict__ rel, const int* __restrict__ ub,
                                                 const int* __restrict__ ct, const int* __restrict__ jt,
                                                 const float* __restrict__ partm, const float* __restrict__ parts,
                                                 float* __restrict__ out) {
    __shared__ float s_u[4][128];
    int w = threadIdx.x >> 6, lane = threadIdx.x & 63;
    int u = blockIdx.x * 4 + w;

    const unsigned short* up = hfin + (size_t)ub[u] * DD;
    float u0 = bf2f(up[lane]), u1 = bf2f(up[lane + 64]);
    s_u[w][lane] = u0;
    s_u[w][lane + 64] = u1;   // same-wave LDS write->read, no barrier needed

    // pos_c / pos_j lane-partials
    const float* tcp = ent + (size_t)(USER_NUM_ + ct[u]) * DD;
    float pc = u0 * tcp[lane] + u1 * tcp[lane + 64];
    const float* tjp = rel + (size_t)jt[u] * DD;
    float pj = u0 * tjp[lane] + u1 * tjp[lane + 64];
#pragma unroll
    for (int o = 1; o < 64; o <<= 1) {
        pc += __shfl_xor(pc, o, 64);
        pj += __shfl_xor(pj, o, 64);
    }

    // merge 125 comp-LSE partials: lane holds p=lane and p=lane+64
    float M = partm[(size_t)u * PPART + lane];
    float S = parts[(size_t)u * PPART + lane];
    if (lane + 64 < PPART)
        lse_merge(M, S, partm[(size_t)u * PPART + lane + 64], parts[(size_t)u * PPART + lane + 64]);
#pragma unroll
    for (int o = 1; o < 64; o <<= 1) {
        float M2 = __shfl_xor(M, o, 64);
        float S2 = __shfl_xor(S, o, 64);
        lse_merge(M, S, M2, S2);
    }
    float lse_c = M + logf(S);

    // job logits: lane owns job j1=lane (<100) and j2=lane+64 (valid lanes 0..35)
    int j1 = lane, j2 = lane + 64;
    bool v2 = j2 < (REL_NUM_ / 2);
    const float* r1 = rel + (size_t)j1 * DD;
    const float* r2 = rel + (size_t)(v2 ? j2 : 0) * DD;
    float d1 = 0.f, d2 = 0.f;
#pragma unroll 16
    for (int k = 0; k < DD; ++k) {
        float uk = s_u[w][k];
        d1 = fmaf(uk, r1[k], d1);
        d2 = fmaf(uk, r2[k], d2);
    }
    float Mj = d1, Sj = 1.f;
    if (v2) lse_push(d2, Mj, Sj);
#pragma unroll
    for (int o = 1; o < 64; o <<= 1) {
        float M2 = __shfl_xor(Mj, o, 64);
        float S2 = __shfl_xor(Sj, o, 64);
        lse_merge(Mj, Sj, M2, S2);
    }
    float lse_j = Mj + logf(Sj);

    if (lane == 0) {
        atomicAdd(&out[0], lse_c - pc);
        atomicAdd(&out[1], lse_j - pj);
    }
}

// ---------------- host ----------------
static inline size_t rup(size_t x) { return (x + 255) & ~(size_t)255; }

extern "C" void kernel_launch(void* const* d_in, const int* in_sizes, int n_in,
                              void* d_out, int out_size, void* d_ws, size_t ws_size,
                              hipStream_t stream) {
    const float* ent_emb = (const float*)d_in[0];
    const float* c0_emb  = (const float*)d_in[1];
    const float* rel_emb = (const float*)d_in[2];
    const float* W_ih    = (const float*)d_in[3];
    const float* W_hh    = (const float*)d_in[4];
    const float* b_ih    = (const float*)d_in[5];
    const float* b_hh    = (const float*)d_in[6];
    const int* src       = (const int*)d_in[7];
    const int* dst       = (const int*)d_in[8];
    const int* rel_idx   = (const int*)d_in[9];
    const int* seed_idx  = (const int*)d_in[10];
    const int* ubatch    = (const int*)d_in[11];
    const int* ctarg     = (const int*)d_in[12];
    const int* jtarg     = (const int*)d_in[13];
    float* out = (float*)d_out;

    const size_t HBH = (size_t)EN * DD * 2;              // bf16 state buffer: 38,400,512

    char* base = (char*)d_ws;
    unsigned short* h0   = (unsigned short*)base;
    unsigned short* h1   = (unsigned short*)(base + HBH);
    unsigned short* cbuf = (unsigned short*)(base + 2 * HBH);

    auto place = [&](int NT, int** off, int** pairs, int** cnt, int** incl, int** cur,
                     int** bsums, short** Wt, float** bsumv, unsigned short** Rbf) -> size_t {
        size_t o = 3 * HBH;
        *off   = (int*)(base + o); o += rup((size_t)NT * ENP * 4);
        *pairs = (int*)(base + o); o += rup((size_t)NT * EE * 4);
        *cnt   = (int*)(base + o); o += rup((size_t)NT * EN * 4);
        *incl  = (int*)(base + o); o += rup((size_t)NT * EN * 4);
        *cur   = (int*)(base + o); o += rup((size_t)NT * EN * 4);
        *bsums = (int*)(base + o); o += rup((size_t)NT * NBLK * 4);
        *Wt    = (short*)(base + o); o += rup(512 * 256 * 2);
        *bsumv = (float*)(base + o); o += rup(512 * 4);
        *Rbf   = (unsigned short*)(base + o); o += rup((size_t)REL_NUM_ * DD * 2);
        return o;
    };

    int *off, *pairs, *cnt, *incl, *cur, *bsums;
    short* Wt; float* bsumv; unsigned short* Rbf;
    size_t need12 = place(TT, &off, &pairs, &cnt, &incl, &cur, &bsums, &Wt, &bsumv, &Rbf);
    int NT = (ws_size >= need12) ? TT : 1;
    if (NT != TT) place(1, &off, &pairs, &cnt, &incl, &cur, &bsums, &Wt, &bsumv, &Rbf);

    // comp-phase buffers alias cbuf region (dead after step loop)
    char* q = (char*)cbuf;
    short* Cbf = (short*)q;            q += rup((size_t)COMP_NUM_ * DD * 2);  // 12.8 MB
    short* Ubf = (short*)q;            q += rup((size_t)BB * DD * 2);
    float* partm = (float*)q;          q += rup((size_t)BB * PPART * 4);
    float* parts = (float*)q;

    hipMemsetAsync(d_out, 0, 2 * sizeof(float), stream);

    const int n4 = EN * DD / 4;
    const int gcpy = (n4 + 255) / 256;
    const int ge = (EE + 255) / 256;

    prepW_k<<<512, 256, 0, stream>>>(W_ih, W_hh, b_ih, b_hh, Wt, bsumv);
    packBF_k<<<gcpy, 256, 0, stream>>>(ent_emb, (ushort4*)h0, n4);
    packBF_k<<<gcpy, 256, 0, stream>>>(c0_emb, (ushort4*)cbuf, n4);
    packBF_k<<<(REL_NUM_ * DD / 4 + 255) / 256, 256, 0, stream>>>(rel_emb, (ushort4*)Rbf, REL_NUM_ * DD / 4);

    auto build = [&](int t0, int nt) {
        zero_i32_k<<<(nt * EN + 255) / 256, 256, 0, stream>>>(cnt, nt * EN);
        hist_k<<<ge * 16, 256, 0, stream>>>(cnt, dst, t0, nt);
        scanA_k<<<dim3(NBLK, nt), 256, 0, stream>>>(cnt, incl, bsums);
        scanB_k<<<nt, 1024, 0, stream>>>(bsums);
        scanC_k<<<dim3(NBLK, nt), 256, 0, stream>>>(cnt, incl, bsums, off, cur);
        reorder_k<<<ge * 16, 256, 0, stream>>>(src, dst, rel_idx, cur, pairs, t0, nt);
    };

    if (NT == TT) build(0, TT);

    unsigned short* hold = h0;
    unsigned short* hnew = h1;
    const int gagg = (EN + 15) / 16;

    for (int t = 0; t < TT; ++t) {
        if (NT == 1) build(t, 1);
        int slot = (NT == TT) ? t : 0;
        agg_k<<<gagg, 256, 0, stream>>>(hold, hnew, Rbf, off, pairs, slot);
        lstm_k<<<SS / 32, 256, 0, stream>>>(hold, hnew, cbuf, Wt, bsumv, seed_idx + (size_t)t * SS);
        unsigned short* tmp = hold; hold = hnew; hnew = tmp;
    }

    // NOTE: cbuf region is reused for Cbf/Ubf/partials from here on
    packBF_k<<<(COMP_NUM_ * DD / 4 + 255) / 256, 256, 0, stream>>>(ent_emb + (size_t)USER_NUM_ * DD,
                                                                   (ushort4*)Cbf, COMP_NUM_ * DD / 4);
    packU_k<<<(BB * DD + 255) / 256, 256, 0, stream>>>(hold, ubatch, Ubf);
    comp_mfma_k<<<dim3(BB / 128, PPART), 256, 0, stream>>>(Ubf, Cbf, partm, parts);
    finish2_k<<<BB / 4, 256, 0, stream>>>(hold, ent_emb, rel_emb, ubatch, ctarg, jtarg,
                                          partm, parts, out);
}

// Round 6
// 1149.628 us; speedup vs baseline: 2.5990x; 1.0035x over previous
//
#include <hip/hip_runtime.h>
#include <math.h>

typedef __attribute__((ext_vector_type(8))) short short8;
typedef __attribute__((ext_vector_type(8))) unsigned short u16x8;
typedef __attribute__((ext_vector_type(4))) float f32x4;

#define USER_NUM_  100000
#define COMP_NUM_  50000
#define EN         150002
#define REL_NUM_   200
#define DD         128
#define TT         12
#define EE         250000
#define SS         20000
#define BB         1024
#define NBLK       587      // ceil(EN/256)
#define PPART      125      // comp partitions
#define TILES_PP   25       // 16-comp tiles per partition (125*25*16 = 50000)

__device__ inline unsigned short f2bf(float f) {
    unsigned u = __float_as_uint(f);
    unsigned r = (u + 0x7fffu + ((u >> 16) & 1u)) >> 16;
    return (unsigned short)r;
}

__device__ inline float bf2f(unsigned short u) {
    return __uint_as_float((unsigned)u << 16);
}

__device__ inline float sigmoidf_(float x) { return 1.f / (1.f + __expf(-x)); }

__device__ inline void lse_push(float v, float& m, float& s) {
    if (v <= m) { s += __expf(v - m); }
    else { s = s * __expf(m - v) + 1.f; m = v; }
}

__device__ inline void lse_merge(float& M, float& S, float M2, float S2) {
    float Mn = fmaxf(M, M2);
    S = S * __expf(M - Mn) + S2 * __expf(M2 - Mn);
    M = Mn;
}

// ---------------- utility ----------------
__global__ __launch_bounds__(256) void packBF_k(const float* __restrict__ src, ushort4* __restrict__ dst, int n4) {
    int i = blockIdx.x * 256 + threadIdx.x;
    if (i >= n4) return;
    float4 v = ((const float4*)src)[i];
    ushort4 o;
    o.x = f2bf(v.x); o.y = f2bf(v.y); o.z = f2bf(v.z); o.w = f2bf(v.w);
    dst[i] = o;
}

__global__ __launch_bounds__(256) void zero_i32_k(int* __restrict__ p, int n) {
    int i = blockIdx.x * 256 + threadIdx.x;
    if (i < n) p[i] = 0;
}

__global__ __launch_bounds__(256) void prepW_k(const float* __restrict__ Wih, const float* __restrict__ Whh,
                                               const float* __restrict__ bih, const float* __restrict__ bhh,
                                               short* __restrict__ Wt, float* __restrict__ bsum) {
    int n = blockIdx.x;      // 0..511
    int k = threadIdx.x;     // 0..255
    float v = (k < 128) ? Wih[n * 128 + k] : Whh[n * 128 + (k - 128)];
    Wt[n * 256 + k] = (short)f2bf(v);
    if (k == 0) bsum[n] = bih[n] + bhh[n];
}

// ---------------- CSR build (in-place scan in startp; slot = blk&15 for XCD affinity) ---
__global__ __launch_bounds__(256) void hist_k(int* __restrict__ startp, const int* __restrict__ dst,
                                              int t0, int nt) {
    int slot = blockIdx.x & 15;
    if (slot >= nt) return;
    int e = (blockIdx.x >> 4) * 256 + threadIdx.x;
    if (e < EE) atomicAdd(&startp[slot * EN + dst[(size_t)(t0 + slot) * EE + e]], 1);
}

// in-place: counts -> block-exclusive scan; bsums[blk] = block total
__global__ __launch_bounds__(256) void scanA_k(int* __restrict__ startp, int* __restrict__ bsums) {
    int slot = blockIdx.y;
    int tid = threadIdx.x;
    int i = blockIdx.x * 256 + tid;
    int v = (i < EN) ? startp[slot * EN + i] : 0;
    __shared__ int lds[256];
    lds[tid] = v; __syncthreads();
#pragma unroll
    for (int o = 1; o < 256; o <<= 1) {
        int x = (tid >= o) ? lds[tid - o] : 0;
        __syncthreads();
        lds[tid] += x;
        __syncthreads();
    }
    if (i < EN) startp[slot * EN + i] = lds[tid] - v;   // exclusive within block
    if (tid == 255) bsums[slot * NBLK + blockIdx.x] = lds[tid];
}

__global__ __launch_bounds__(1024) void scanB_k(int* __restrict__ bsums) {
    int slot = blockIdx.x;
    int tid = threadIdx.x;
    int v = (tid < NBLK) ? bsums[slot * NBLK + tid] : 0;
    __shared__ int lds[1024];
    lds[tid] = v; __syncthreads();
#pragma unroll
    for (int o = 1; o < 1024; o <<= 1) {
        int x = (tid >= o) ? lds[tid - o] : 0;
        __syncthreads();
        lds[tid] += x;
        __syncthreads();
    }
    if (tid < NBLK) bsums[slot * NBLK + tid] = lds[tid] - v;  // exclusive block bases
}

__global__ __launch_bounds__(256) void scanC_k(int* __restrict__ startp, const int* __restrict__ bsums) {
    int slot = blockIdx.y;
    int i = blockIdx.x * 256 + threadIdx.x;
    if (i < EN) startp[slot * EN + i] += bsums[slot * NBLK + blockIdx.x];
}

// atomicAdd mutates startp from start-offsets to end-offsets in place
__global__ __launch_bounds__(256) void reorder_k(const int* __restrict__ src, const int* __restrict__ dst,
                                                 const int* __restrict__ rel, int* __restrict__ startp,
                                                 int* __restrict__ pairs, int t0, int nt) {
    int slot = blockIdx.x & 15;
    if (slot >= nt) return;
    int e = (blockIdx.x >> 4) * 256 + threadIdx.x;
    if (e >= EE) return;
    size_t gi = (size_t)(t0 + slot) * EE + e;
    int d = dst[gi];
    int pos = atomicAdd(&startp[slot * EN + d], 1);
    pairs[(size_t)slot * EE + pos] = src[gi] | (rel[gi] << 18);
}

// ---------------- fused aggregate: x[d] = h[d] + (1/cnt)*sum h[src]*rel[r] (bf16) -------
// endp = post-reorder startp (holds end offsets). e0 = endp[d-1] (0 for d==0).
// 16 lanes per entity (8 bf16 = 16B each), 16 entities per 256-block.
__global__ __launch_bounds__(256) void agg_k(const unsigned short* __restrict__ hold,
                                             unsigned short* __restrict__ hnew,
                                             const unsigned short* __restrict__ Rbf,
                                             const int* __restrict__ endp_all,
                                             const int* __restrict__ pairs, int slot) {
    int tid = threadIdx.x;
    int d = blockIdx.x * 16 + (tid >> 4);
    int l = tid & 15;
    if (d >= EN) return;
    const int* endp = endp_all + (size_t)slot * EN;
    int e0 = (d > 0) ? endp[d - 1] : 0;
    int e1 = endp[d];
    const int* pp = pairs + (size_t)slot * EE;
    float acc[8];
#pragma unroll
    for (int j = 0; j < 8; ++j) acc[j] = 0.f;
    int e = e0;
    for (; e + 2 <= e1; e += 2) {
        int pk0 = pp[e], pk1 = pp[e + 1];
        u16x8 h0 = *(const u16x8*)(hold + (size_t)(pk0 & 0x3FFFF) * DD + l * 8);
        u16x8 r0 = *(const u16x8*)(Rbf + (size_t)(pk0 >> 18) * DD + l * 8);
        u16x8 h1 = *(const u16x8*)(hold + (size_t)(pk1 & 0x3FFFF) * DD + l * 8);
        u16x8 r1 = *(const u16x8*)(Rbf + (size_t)(pk1 >> 18) * DD + l * 8);
#pragma unroll
        for (int j = 0; j < 8; ++j)
            acc[j] = fmaf(bf2f(h1[j]), bf2f(r1[j]), fmaf(bf2f(h0[j]), bf2f(r0[j]), acc[j]));
    }
    if (e < e1) {
        int pk0 = pp[e];
        u16x8 h0 = *(const u16x8*)(hold + (size_t)(pk0 & 0x3FFFF) * DD + l * 8);
        u16x8 r0 = *(const u16x8*)(Rbf + (size_t)(pk0 >> 18) * DD + l * 8);
#pragma unroll
        for (int j = 0; j < 8; ++j)
            acc[j] = fmaf(bf2f(h0[j]), bf2f(r0[j]), acc[j]);
    }
    u16x8 hd = *(const u16x8*)(hold + (size_t)d * DD + l * 8);
    int c = e1 - e0;
    float inv = (c > 0) ? 1.f / (float)c : 0.f;
    u16x8 o;
#pragma unroll
    for (int j = 0; j < 8; ++j) o[j] = f2bf(fmaf(acc[j], inv, bf2f(hd[j])));
    *(u16x8*)(hnew + (size_t)d * DD + l * 8) = o;
}

// ---------------- LSTM on seed rows (MFMA bf16; bf16 h and c state) ----------------
__global__ __launch_bounds__(256) void lstm_k(const unsigned short* __restrict__ hold,
                                              unsigned short* __restrict__ hnew,
                                              unsigned short* __restrict__ cbuf, const short* __restrict__ Wt,
                                              const float* __restrict__ bsum, const int* __restrict__ seed) {
    int w = threadIdx.x >> 6;
    int lane = threadIdx.x & 63;
    int lrow = lane & 15, lhi = lane >> 4;
    int m0 = blockIdx.x * 32;
    int w32 = w * 32;

    const unsigned short* pxi[2];
    const unsigned short* php[2];
#pragma unroll
    for (int mi = 0; mi < 2; ++mi) {
        int m = m0 + mi * 16 + lrow;
        int sd = seed[m];
        pxi[mi] = hnew + (size_t)sd * DD;
        php[mi] = hold + (size_t)sd * DD;
    }

    f32x4 acc[2][4][2];
#pragma unroll
    for (int mi = 0; mi < 2; ++mi)
#pragma unroll
        for (int g = 0; g < 4; ++g)
#pragma unroll
            for (int s = 0; s < 2; ++s)
                acc[mi][g][s] = (f32x4){0.f, 0.f, 0.f, 0.f};

#pragma unroll
    for (int kk = 0; kk < 8; ++kk) {
        int klane = kk * 32 + lhi * 8;
        short8 af[2];
#pragma unroll
        for (int mi = 0; mi < 2; ++mi) {
            const unsigned short* p = (klane < 128) ? (pxi[mi] + klane) : (php[mi] + (klane - 128));
            af[mi] = *(const short8*)p;
        }
#pragma unroll
        for (int g = 0; g < 4; ++g)
#pragma unroll
            for (int s = 0; s < 2; ++s) {
                int col = g * 128 + w32 + s * 16 + lrow;
                short8 bf = *(const short8*)(Wt + col * 256 + klane);
                acc[0][g][s] = __builtin_amdgcn_mfma_f32_16x16x32_bf16(af[0], bf, acc[0][g][s], 0, 0, 0);
                acc[1][g][s] = __builtin_amdgcn_mfma_f32_16x16x32_bf16(af[1], bf, acc[1][g][s], 0, 0, 0);
            }
    }

    __syncthreads();  // all xi reads done before seed rows are overwritten

#pragma unroll
    for (int mi = 0; mi < 2; ++mi) {
#pragma unroll
        for (int r = 0; r < 4; ++r) {
            int m = m0 + mi * 16 + lhi * 4 + r;
            int sd = seed[m];
#pragma unroll
            for (int s = 0; s < 2; ++s) {
                int d = w32 + s * 16 + lrow;
                float ig = acc[mi][0][s][r] + bsum[d];
                float fg = acc[mi][1][s][r] + bsum[128 + d];
                float gg = acc[mi][2][s][r] + bsum[256 + d];
                float og = acc[mi][3][s][r] + bsum[384 + d];
                float cp = bf2f(cbuf[(size_t)sd * DD + d]);
                float cn = sigmoidf_(fg) * cp + sigmoidf_(ig) * tanhf(gg);
                float hn = sigmoidf_(og) * tanhf(cn);
                cbuf[(size_t)sd * DD + d] = f2bf(cn);
                hnew[(size_t)sd * DD + d] = f2bf(hn);
            }
        }
    }
}

// ---------------- comp loss: bf16 packers ----------------
__global__ __launch_bounds__(256) void packU_k(const unsigned short* __restrict__ hfin, const int* __restrict__ ub,
                                               short* __restrict__ Ubf) {
    int i = blockIdx.x * 256 + threadIdx.x;    // over 1024*128
    if (i >= BB * DD) return;
    int u = i >> 7, k = i & 127;
    Ubf[i] = (short)hfin[(size_t)ub[u] * DD + k];
}

// ---------------- comp loss: MFMA GEMM + per-lane online LSE ----------------
__global__ __launch_bounds__(256) void comp_mfma_k(const short* __restrict__ Ubf, const short* __restrict__ Cbf,
                                                   float* __restrict__ partm, float* __restrict__ parts) {
    int w = threadIdx.x >> 6, lane = threadIdx.x & 63;
    int lrow = lane & 15, lhi = lane >> 4;
    int ubase = blockIdx.x * 128 + w * 32;
    int p = blockIdx.y;

    short8 a[2][4];
#pragma unroll
    for (int s2 = 0; s2 < 2; ++s2)
#pragma unroll
        for (int kc = 0; kc < 4; ++kc)
            a[s2][kc] = *(const short8*)(Ubf + (size_t)(ubase + s2 * 16 + lrow) * DD + kc * 32 + lhi * 8);

    float m[2][4], s[2][4];
#pragma unroll
    for (int s2 = 0; s2 < 2; ++s2)
#pragma unroll
        for (int r = 0; r < 4; ++r) { m[s2][r] = -1e30f; s[s2][r] = 0.f; }

    int c0 = p * TILES_PP * 16;
    for (int tile = 0; tile < TILES_PP; ++tile) {
        int comp = c0 + tile * 16 + lrow;
        f32x4 acc0 = {0.f, 0.f, 0.f, 0.f};
        f32x4 acc1 = {0.f, 0.f, 0.f, 0.f};
#pragma unroll
        for (int kc = 0; kc < 4; ++kc) {
            short8 b = *(const short8*)(Cbf + (size_t)comp * DD + kc * 32 + lhi * 8);
            acc0 = __builtin_amdgcn_mfma_f32_16x16x32_bf16(a[0][kc], b, acc0, 0, 0, 0);
            acc1 = __builtin_amdgcn_mfma_f32_16x16x32_bf16(a[1][kc], b, acc1, 0, 0, 0);
        }
#pragma unroll
        for (int r = 0; r < 4; ++r) {
            lse_push(acc0[r], m[0][r], s[0][r]);
            lse_push(acc1[r], m[1][r], s[1][r]);
        }
    }

#pragma unroll
    for (int s2 = 0; s2 < 2; ++s2)
#pragma unroll
        for (int r = 0; r < 4; ++r) {
            float M = m[s2][r], S = s[s2][r];
#pragma unroll
            for (int o = 1; o < 16; o <<= 1) {
                float M2 = __shfl_xor(M, o, 64);
                float S2 = __shfl_xor(S, o, 64);
                if (M2 > M) { S = S * __expf(M - M2) + S2; M = M2; }
                else { S += S2 * __expf(M2 - M); }
            }
            if (lrow == 0) {
                int u = ubase + s2 * 16 + lhi * 4 + r;
                partm[(size_t)u * PPART + p] = M;
                parts[(size_t)u * PPART + p] = S;
            }
        }
}

// ---------------- finish (wave-per-user) ----------------
__global__ __launch_bounds__(256) void finish2_k(const unsigned short* __restrict__ hfin,
                                                 const float* __restrict__ ent,
                                                 const float* __restrict__ rel, const int* __restrict__ ub,
                                                 const int* __restrict__ ct, const int* __restrict__ jt,
                                                 const float* __restrict__ partm, const float* __restrict__ parts,
                                                 float* __restrict__ out) {
    __shared__ float s_u[4][128];
    int w = threadIdx.x >> 6, lane = threadIdx.x & 63;
    int u = blockIdx.x * 4 + w;

    const unsigned short* up = hfin + (size_t)ub[u] * DD;
    float u0 = bf2f(up[lane]), u1 = bf2f(up[lane + 64]);
    s_u[w][lane] = u0;
    s_u[w][lane + 64] = u1;   // same-wave LDS write->read, no barrier needed

    // pos_c / pos_j lane-partials
    const float* tcp = ent + (size_t)(USER_NUM_ + ct[u]) * DD;
    float pc = u0 * tcp[lane] + u1 * tcp[lane + 64];
    const float* tjp = rel + (size_t)jt[u] * DD;
    float pj = u0 * tjp[lane] + u1 * tjp[lane + 64];
#pragma unroll
    for (int o = 1; o < 64; o <<= 1) {
        pc += __shfl_xor(pc, o, 64);
        pj += __shfl_xor(pj, o, 64);
    }

    // merge 125 comp-LSE partials: lane holds p=lane and p=lane+64
    float M = partm[(size_t)u * PPART + lane];
    float S = parts[(size_t)u * PPART + lane];
    if (lane + 64 < PPART)
        lse_merge(M, S, partm[(size_t)u * PPART + lane + 64], parts[(size_t)u * PPART + lane + 64]);
#pragma unroll
    for (int o = 1; o < 64; o <<= 1) {
        float M2 = __shfl_xor(M, o, 64);
        float S2 = __shfl_xor(S, o, 64);
        lse_merge(M, S, M2, S2);
    }
    float lse_c = M + logf(S);

    // job logits: lane owns job j1=lane (<100) and j2=lane+64 (valid lanes 0..35)
    int j1 = lane, j2 = lane + 64;
    bool v2 = j2 < (REL_NUM_ / 2);
    const float* r1 = rel + (size_t)j1 * DD;
    const float* r2 = rel + (size_t)(v2 ? j2 : 0) * DD;
    float d1 = 0.f, d2 = 0.f;
#pragma unroll 16
    for (int k = 0; k < DD; ++k) {
        float uk = s_u[w][k];
        d1 = fmaf(uk, r1[k], d1);
        d2 = fmaf(uk, r2[k], d2);
    }
    float Mj = d1, Sj = 1.f;
    if (v2) lse_push(d2, Mj, Sj);
#pragma unroll
    for (int o = 1; o < 64; o <<= 1) {
        float M2 = __shfl_xor(Mj, o, 64);
        float S2 = __shfl_xor(Sj, o, 64);
        lse_merge(Mj, Sj, M2, S2);
    }
    float lse_j = Mj + logf(Sj);

    if (lane == 0) {
        atomicAdd(&out[0], lse_c - pc);
        atomicAdd(&out[1], lse_j - pj);
    }
}

// ---------------- host ----------------
static inline size_t rup(size_t x) { return (x + 255) & ~(size_t)255; }

extern "C" void kernel_launch(void* const* d_in, const int* in_sizes, int n_in,
                              void* d_out, int out_size, void* d_ws, size_t ws_size,
                              hipStream_t stream) {
    const float* ent_emb = (const float*)d_in[0];
    const float* c0_emb  = (const float*)d_in[1];
    const float* rel_emb = (const float*)d_in[2];
    const float* W_ih    = (const float*)d_in[3];
    const float* W_hh    = (const float*)d_in[4];
    const float* b_ih    = (const float*)d_in[5];
    const float* b_hh    = (const float*)d_in[6];
    const int* src       = (const int*)d_in[7];
    const int* dst       = (const int*)d_in[8];
    const int* rel_idx   = (const int*)d_in[9];
    const int* seed_idx  = (const int*)d_in[10];
    const int* ubatch    = (const int*)d_in[11];
    const int* ctarg     = (const int*)d_in[12];
    const int* jtarg     = (const int*)d_in[13];
    float* out = (float*)d_out;

    const size_t HBH = (size_t)EN * DD * 2;              // bf16 state buffer: 38,400,512

    char* base = (char*)d_ws;
    unsigned short* h0   = (unsigned short*)base;
    unsigned short* h1   = (unsigned short*)(base + HBH);
    unsigned short* cbuf = (unsigned short*)(base + 2 * HBH);

    int* startp; int* pairs; int* bsums;
    short* Wt; float* bsumv; unsigned short* Rbf;
    auto place = [&](int NT) -> size_t {
        size_t o = 3 * HBH;
        startp = (int*)(base + o); o += rup((size_t)NT * EN * 4);
        pairs  = (int*)(base + o); o += rup((size_t)NT * EE * 4);
        bsums  = (int*)(base + o); o += rup((size_t)NT * NBLK * 4);
        Wt     = (short*)(base + o); o += rup(512 * 256 * 2);
        bsumv  = (float*)(base + o); o += rup(512 * 4);
        Rbf    = (unsigned short*)(base + o); o += rup((size_t)REL_NUM_ * DD * 2);
        return o;
    };

    const int cands[6] = {12, 6, 4, 3, 2, 1};
    int NT = 1;
    for (int i = 0; i < 6; ++i) {
        if (place(cands[i]) <= ws_size) { NT = cands[i]; break; }
    }
    place(NT);  // final pointers

    // comp-phase buffers alias cbuf region (dead after step loop)
    char* q = (char*)cbuf;
    short* Cbf = (short*)q;            q += rup((size_t)COMP_NUM_ * DD * 2);  // 12.8 MB
    short* Ubf = (short*)q;            q += rup((size_t)BB * DD * 2);
    float* partm = (float*)q;          q += rup((size_t)BB * PPART * 4);
    float* parts = (float*)q;

    hipMemsetAsync(d_out, 0, 2 * sizeof(float), stream);

    const int n4 = EN * DD / 4;
    const int gcpy = (n4 + 255) / 256;
    const int ge = (EE + 255) / 256;

    prepW_k<<<512, 256, 0, stream>>>(W_ih, W_hh, b_ih, b_hh, Wt, bsumv);
    packBF_k<<<gcpy, 256, 0, stream>>>(ent_emb, (ushort4*)h0, n4);
    packBF_k<<<gcpy, 256, 0, stream>>>(c0_emb, (ushort4*)cbuf, n4);
    packBF_k<<<(REL_NUM_ * DD / 4 + 255) / 256, 256, 0, stream>>>(rel_emb, (ushort4*)Rbf, REL_NUM_ * DD / 4);

    auto build = [&](int t0, int nt) {
        zero_i32_k<<<(nt * EN + 255) / 256, 256, 0, stream>>>(startp, nt * EN);
        hist_k<<<ge * 16, 256, 0, stream>>>(startp, dst, t0, nt);
        scanA_k<<<dim3(NBLK, nt), 256, 0, stream>>>(startp, bsums);
        scanB_k<<<nt, 1024, 0, stream>>>(bsums);
        scanC_k<<<dim3(NBLK, nt), 256, 0, stream>>>(startp, bsums);
        reorder_k<<<ge * 16, 256, 0, stream>>>(src, dst, rel_idx, startp, pairs, t0, nt);
    };

    unsigned short* hold = h0;
    unsigned short* hnew = h1;
    const int gagg = (EN + 15) / 16;

    for (int b0 = 0; b0 < TT; b0 += NT) {
        int nb = (TT - b0 < NT) ? (TT - b0) : NT;
        build(b0, nb);
        for (int k = 0; k < nb; ++k) {
            int t = b0 + k;
            agg_k<<<gagg, 256, 0, stream>>>(hold, hnew, Rbf, startp, pairs, k);
            lstm_k<<<SS / 32, 256, 0, stream>>>(hold, hnew, cbuf, Wt, bsumv, seed_idx + (size_t)t * SS);
            unsigned short* tmp = hold; hold = hnew; hnew = tmp;
        }
    }

    // NOTE: cbuf region is reused for Cbf/Ubf/partials from here on
    packBF_k<<<(COMP_NUM_ * DD / 4 + 255) / 256, 256, 0, stream>>>(ent_emb + (size_t)USER_NUM_ * DD,
                                                                   (ushort4*)Cbf, COMP_NUM_ * DD / 4);
    packU_k<<<(BB * DD + 255) / 256, 256, 0, stream>>>(hold, ubatch, Ubf);
    comp_mfma_k<<<dim3(BB / 128, PPART), 256, 0, stream>>>(Ubf, Cbf, partm, parts);
    finish2_k<<<BB / 4, 256, 0, stream>>>(hold, ent_emb, rel_emb, ubatch, ctarg, jtarg,
                                          partm, parts, out);
}